// Round 5
// baseline (1531.960 us; speedup 1.0000x reference)
//
#include <hip/hip_runtime.h>
#include <hip/hip_bf16.h>
#include <cstddef>

// Problem constants (fixed by reference)
#define N_USERS   100000
#define N_ITEMS   100000
#define N_NODES   200000
#define D         64
#define BATCH     2048
#define HIST      50
#define N_ITEMS_PAD 100096   // padded to multiple of 128 (block item-chunk)

typedef __attribute__((ext_vector_type(8))) short short8;
typedef __attribute__((ext_vector_type(16))) float float16;

__device__ __forceinline__ ushort f2bf(float x) {  // fp32 -> bf16 RNE
    unsigned u = __float_as_uint(x);
    return (ushort)((u + 0x7FFF + ((u >> 16) & 1)) >> 16);
}
__device__ __forceinline__ float bfu(ushort u) {   // bf16 -> fp32
    return __uint_as_float(((unsigned)u) << 16);
}
__device__ __forceinline__ unsigned char f2fp8(float x) {  // fp32 -> fp8 e4m3 (OCP), RNE+sat
    int p = __builtin_amdgcn_cvt_pk_fp8_f32(x, x, 0, false);
    return (unsigned char)(p & 0xFF);
}
__device__ __forceinline__ float fp82f(unsigned char u) {  // fp8 e4m3 -> fp32
    return __builtin_amdgcn_cvt_f32_fp8((int)u, 0);
}

// ---------------- CSR build ----------------
__global__ void k_hist(const int* __restrict__ adj_row, int* __restrict__ deg, int nedges) {
    int e = blockIdx.x * 256 + threadIdx.x;
    if (e < nedges) atomicAdd(&deg[adj_row[e]], 1);
}

// ---------------- init: w0 = fp8( 64 * x0 / sqrt(max(deg,1)) )  (z-space, scaled by 64) ----------------
__global__ void k_init(const float* __restrict__ user_emb, const float* __restrict__ item_emb,
                       const int* __restrict__ deg, unsigned char* __restrict__ w0) {
    int f = blockIdx.x * 256 + threadIdx.x;              // one 4-dim group
    if (f >= N_NODES * (D / 4)) return;
    int row = f >> 4;
    const float4* src = (row < N_USERS)
        ? ((const float4*)user_emb) + (size_t)row * 16 + (f & 15)
        : ((const float4*)item_emb) + (size_t)(row - (N_USERS - 1)) * 16 + (f & 15);
    float4 v = *src;
    int dg = deg[row]; if (dg < 1) dg = 1;
    float sc = 64.f * __frsqrt_rn((float)dg);
    uchar4 o;
    o.x = f2fp8(v.x * sc); o.y = f2fp8(v.y * sc);
    o.z = f2fp8(v.z * sc); o.w = f2fp8(v.w * sc);
    ((uchar4*)w0)[f] = o;
}

__global__ __launch_bounds__(256) void k_scan_block(const int* __restrict__ deg,
                                                    int* __restrict__ rowptr, int* __restrict__ bsums) {
    __shared__ int s[256];
    int t = threadIdx.x;
    int base = blockIdx.x * 1024 + t * 4;
    int d[4]; int tsum = 0;
#pragma unroll
    for (int k = 0; k < 4; ++k) { d[k] = (base + k < N_NODES) ? deg[base + k] : 0; tsum += d[k]; }
    s[t] = tsum; __syncthreads();
    for (int off = 1; off < 256; off <<= 1) {
        int v = (t >= off) ? s[t - off] : 0;
        __syncthreads();
        s[t] += v;
        __syncthreads();
    }
    int excl = s[t] - tsum;
    int run = excl;
#pragma unroll
    for (int k = 0; k < 4; ++k) { if (base + k < N_NODES) rowptr[base + k] = run; run += d[k]; }
    if (t == 255) bsums[blockIdx.x] = s[255];
}

__global__ __launch_bounds__(256) void k_scan_sums(int* __restrict__ bsums, int nb) {
    __shared__ int s[256];
    int t = threadIdx.x;
    int v0 = (t < nb) ? bsums[t] : 0;
    s[t] = v0; __syncthreads();
    for (int off = 1; off < 256; off <<= 1) {
        int v = (t >= off) ? s[t - off] : 0;
        __syncthreads();
        s[t] += v;
        __syncthreads();
    }
    if (t < nb) bsums[t] = s[t] - v0;   // exclusive
}

__global__ void k_scan_add(int* __restrict__ rowptr, int* __restrict__ cursor,
                           const int* __restrict__ bsums, int nedges) {
    int i = blockIdx.x * 256 + threadIdx.x;
    if (i < N_NODES) {
        int v = rowptr[i] + bsums[i >> 10];
        rowptr[i] = v;
        cursor[i] = v;          // scatter cursor starts at row base
    }
    if (i == 0) rowptr[N_NODES] = nedges;
}

// scatter only the column, pre-shifted to a byte offset (col*64); no value needed in z-space
__global__ void k_scatter(const int* __restrict__ adj_row, const int* __restrict__ adj_col,
                          int* __restrict__ cursor, int* __restrict__ ecols, int nedges) {
    int e = blockIdx.x * 256 + threadIdx.x;
    if (e >= nedges) return;
    int r = adj_row[e];
    int p = atomicAdd(&cursor[r], 1);
    ecols[p] = adj_col[e] << 6;
}

// ---------------- propagate (fp8 z-space): w_out[r] = (1/deg_r) * sum w_in[c] ----------------
// one wave per row, lane = dim (1 byte/lane -> one 64B line per edge gather)
__global__ __launch_bounds__(256) void k_prop(const int* __restrict__ rowptr, const int* __restrict__ ecols,
                                              const unsigned char* __restrict__ x_in,
                                              unsigned char* __restrict__ x_out) {
    int w = blockIdx.x * 4 + (threadIdx.x >> 6);
    int lane = threadIdx.x & 63;
    int s = rowptr[w], e = rowptr[w + 1];
    float sum = 0.f;
    int p = s;
    for (; p + 8 <= e; p += 8) {
        int c[8];
#pragma unroll
        for (int j = 0; j < 8; ++j) c[j] = ecols[p + j];   // wave-uniform -> s_load_dwordx8
        float xv[8];
#pragma unroll
        for (int j = 0; j < 8; ++j) xv[j] = fp82f(x_in[c[j] + lane]);
#pragma unroll
        for (int j = 0; j < 8; ++j) sum += xv[j];
    }
    for (; p < e; ++p) sum += fp82f(x_in[ecols[p] + lane]);
    int cnt = e - s;
    float wv = (cnt > 0) ? sum / (float)cnt : 0.f;
    x_out[w * D + lane] = f2fp8(wv);
}

// ---------------- item latents: bf16( 0.25*item_emb + sqrt(deg)/256*(w1+w2+w3) ), zero-pad ----------------
__global__ void k_conv_items(const float* __restrict__ item_emb, const int* __restrict__ deg,
                             const unsigned char* __restrict__ w1, const unsigned char* __restrict__ w2,
                             const unsigned char* __restrict__ w3, ushort* __restrict__ item_bf) {
    int f = blockIdx.x * 256 + threadIdx.x;    // one 4-dim group
    if (f >= N_ITEMS_PAD * (D / 4)) return;
    int row = f >> 4, c4 = f & 15;
    ushort4 o;
    if (row < N_ITEMS) {
        int node = N_USERS + row;
        int dg = deg[node]; if (dg < 1) dg = 1;
        float s = sqrtf((float)dg) * (1.f / 256.f);    // sqrt(deg)/(64 scale * 4 avg)
        float4 e4 = ((const float4*)(item_emb + (size_t)(row + 1) * D))[c4];
        size_t n4 = (size_t)node * 16 + c4;
        uchar4 a = ((const uchar4*)w1)[n4];
        uchar4 b = ((const uchar4*)w2)[n4];
        uchar4 c = ((const uchar4*)w3)[n4];
        o.x = f2bf(0.25f * e4.x + s * (fp82f(a.x) + fp82f(b.x) + fp82f(c.x)));
        o.y = f2bf(0.25f * e4.y + s * (fp82f(a.y) + fp82f(b.y) + fp82f(c.y)));
        o.z = f2bf(0.25f * e4.z + s * (fp82f(a.z) + fp82f(b.z) + fp82f(c.z)));
        o.w = f2bf(0.25f * e4.w + s * (fp82f(a.w) + fp82f(b.w) + fp82f(c.w)));
    } else {
        o.x = o.y = o.z = o.w = 0;   // pad rows -> score 0 -> exp = 1 (subtract 96 in k_loss)
    }
    ((ushort4*)item_bf)[f] = o;
}

// ---------------- pred (bf16 copy) + label score ----------------
__global__ __launch_bounds__(256) void k_pred(const int* __restrict__ user_seqs, const int* __restrict__ his,
                                              const int* __restrict__ next_items,
                                              const float* __restrict__ user_emb, const float* __restrict__ item_emb,
                                              const int* __restrict__ deg,
                                              const unsigned char* __restrict__ w1, const unsigned char* __restrict__ w2,
                                              const unsigned char* __restrict__ w3,
                                              ushort* __restrict__ pred_bf, float* __restrict__ slabel) {
    int b = blockIdx.x * 4 + (threadIdx.x >> 6);
    int lane = threadIdx.x & 63;
    int u = user_seqs[b];
    float hsum = 0.f; int cnt = 0;
    for (int j = 0; j < HIST; ++j) {
        int it = his[b * HIST + j];
        cnt += (it != 0);
        hsum += item_emb[(size_t)it * D + lane];   // item_emb[0] is all-zero (pad)
    }
    int du = deg[u]; if (du < 1) du = 1;
    float su = sqrtf((float)du) * (1.f / 256.f);
    size_t ur = (size_t)u * D + lane;
    float ulat = 0.25f * user_emb[ur] + su * (fp82f(w1[ur]) + fp82f(w2[ur]) + fp82f(w3[ur]));
    float pv = ulat + hsum / (float)cnt;
    pred_bf[(size_t)b * D + lane] = f2bf(pv);
    int lab = next_items[b] - 1;
    int node = N_USERS + lab;
    int di = deg[node]; if (di < 1) di = 1;
    float si = sqrtf((float)di) * (1.f / 256.f);
    size_t nr = (size_t)node * D + lane;
    float ilat = 0.25f * item_emb[(size_t)(lab + 1) * D + lane]
               + si * (fp82f(w1[nr]) + fp82f(w2[nr]) + fp82f(w3[nr]));
    float tv = pv * ilat;
#pragma unroll
    for (int off = 32; off > 0; off >>= 1) tv += __shfl_down(tv, off);
    if (lane == 0) slabel[b] = tv;
}

// ---------------- MFMA scores + max-free sumexp ----------------
__global__ __launch_bounds__(256) void k_scores(const ushort* __restrict__ item_bf,
                                                const ushort* __restrict__ pred_bf,
                                                float* __restrict__ sumexp) {
    __shared__ float lds[4 * 2048];  // 4 waves x 2048 floats = 32 KB
    int t = threadIdx.x, wv = t >> 6, lane = t & 63;
    for (int i = t; i < 4 * 2048; i += 256) lds[i] = 0.f;
    __syncthreads();

    int item0 = blockIdx.x * 128 + wv * 32 + (lane & 31);
    int khalf = (lane >> 5) * 8;   // which 8-elem k-half this lane holds

    const ushort* ib = item_bf + (size_t)item0 * D + khalf;
    short8 afrag[4];
#pragma unroll
    for (int tt = 0; tt < 4; ++tt) afrag[tt] = *(const short8*)(ib + 16 * tt);

    float* myld = lds + wv * 2048;
    for (int mi = 0; mi < 64; ++mi) {
        int mtile = mi * 32;
        const ushort* pb = pred_bf + (size_t)(mtile + (lane & 31)) * D + khalf;
        short8 b0 = *(const short8*)(pb);
        short8 b1 = *(const short8*)(pb + 16);
        short8 b2 = *(const short8*)(pb + 32);
        short8 b3 = *(const short8*)(pb + 48);
        float16 c = {0.f};
        c = __builtin_amdgcn_mfma_f32_32x32x16_bf16(afrag[0], b0, c, 0, 0, 0);
        c = __builtin_amdgcn_mfma_f32_32x32x16_bf16(afrag[1], b1, c, 0, 0, 0);
        c = __builtin_amdgcn_mfma_f32_32x32x16_bf16(afrag[2], b2, c, 0, 0, 0);
        c = __builtin_amdgcn_mfma_f32_32x32x16_bf16(afrag[3], b3, c, 0, 0, 0);
        float part = 0.f;
#pragma unroll
        for (int r = 0; r < 16; ++r) part += __expf(c[r]);
        part += __shfl_down(part, 32);          // fold the two col-duplicate half-waves
        if (lane < 32) {
            float* p = myld + mtile + lane;     // wave-private, conflict-free
            *p += part;
        }
    }
    __syncthreads();
    for (int m = t; m < 2048; m += 256) {
        float v = lds[m] + lds[2048 + m] + lds[4096 + m] + lds[6144 + m];
        unsafeAtomicAdd(&sumexp[m], v);
    }
}

// ---------------- final loss reduce ----------------
__global__ __launch_bounds__(256) void k_loss(const float* __restrict__ sumexp, const float* __restrict__ slabel,
                                              float* __restrict__ out) {
    __shared__ float ws[4];
    int t = threadIdx.x;
    float v = 0.f;
    for (int i = t; i < BATCH; i += 256)
        v += __logf(sumexp[i] - 96.0f) - slabel[i];   // -96: padded items contribute exp(0)=1 each
#pragma unroll
    for (int off = 32; off > 0; off >>= 1) v += __shfl_down(v, off);
    if ((t & 63) == 0) ws[t >> 6] = v;
    __syncthreads();
    if (t == 0) out[0] = (ws[0] + ws[1] + ws[2] + ws[3]) * (1.f / (float)BATCH);
}

extern "C" void kernel_launch(void* const* d_in, const int* in_sizes, int n_in,
                              void* d_out, int out_size, void* d_ws, size_t ws_size,
                              hipStream_t stream) {
    const int*   user_seqs = (const int*)d_in[0];
    const int*   his       = (const int*)d_in[1];
    const int*   next_itm  = (const int*)d_in[2];
    const int*   adj_row   = (const int*)d_in[3];
    const int*   adj_col   = (const int*)d_in[4];
    const float* user_emb  = (const float*)d_in[6];
    const float* item_emb  = (const float*)d_in[7];
    float* out = (float*)d_out;
    int nedges = in_sizes[3];   // 12,800,000

    // Workspace layout (~117 MB)
    unsigned char* w0 = (unsigned char*)d_ws;              // 12.8 MB each
    unsigned char* w1 = w0 + (size_t)N_NODES * D;
    unsigned char* w2 = w1 + (size_t)N_NODES * D;
    unsigned char* w3 = w2 + (size_t)N_NODES * D;
    float*  slabel = (float*)(w3 + (size_t)N_NODES * D);   // 2,048
    float*  sumexp = slabel + BATCH;                       // 2,048   (zeroed)
    int*    deg    = (int*)(sumexp + BATCH);               // 200,000 (zeroed)
    int*    cursor = deg + N_NODES;                        // 200,000
    int*    rowptr = cursor + N_NODES;                     // 200,002
    int*    bsums  = rowptr + (N_NODES + 2);               // 256
    int*    ecols  = bsums + 256;                          // 12.8M ints (51.2 MB)
    ushort* item_bf = (ushort*)(ecols + (size_t)nedges);   // 100096*64 ushort
    ushort* pred_bf = item_bf + (size_t)N_ITEMS_PAD * D;   // 131072 ushort

    // zero sumexp + deg (cursor is overwritten by k_scan_add)
    hipError_t _e = hipMemsetAsync(sumexp, 0, (size_t)(BATCH + N_NODES) * sizeof(int), stream);
    (void)_e;

    k_hist<<<(nedges + 255) / 256, 256, 0, stream>>>(adj_row, deg, nedges);
    k_init<<<(N_NODES * (D / 4) + 255) / 256, 256, 0, stream>>>(user_emb, item_emb, deg, w0);

    int nsb = (N_NODES + 1023) / 1024;  // 196
    k_scan_block<<<nsb, 256, 0, stream>>>(deg, rowptr, bsums);
    k_scan_sums<<<1, 256, 0, stream>>>(bsums, nsb);
    k_scan_add<<<(N_NODES + 255) / 256, 256, 0, stream>>>(rowptr, cursor, bsums, nedges);
    k_scatter<<<(nedges + 255) / 256, 256, 0, stream>>>(adj_row, adj_col, cursor, ecols, nedges);

    k_prop<<<N_NODES / 4, 256, 0, stream>>>(rowptr, ecols, w0, w1);
    k_prop<<<N_NODES / 4, 256, 0, stream>>>(rowptr, ecols, w1, w2);
    k_prop<<<N_NODES / 4, 256, 0, stream>>>(rowptr, ecols, w2, w3);

    k_conv_items<<<(N_ITEMS_PAD * (D / 4) + 255) / 256, 256, 0, stream>>>(item_emb, deg, w1, w2, w3, item_bf);
    k_pred<<<BATCH / 4, 256, 0, stream>>>(user_seqs, his, next_itm, user_emb, item_emb, deg,
                                          w1, w2, w3, pred_bf, slabel);

    k_scores<<<N_ITEMS_PAD / 128, 256, 0, stream>>>(item_bf, pred_bf, sumexp);

    k_loss<<<1, 256, 0, stream>>>(sumexp, slabel, out);
}

// Round 6
// 1167.139 us; speedup vs baseline: 1.3126x; 1.3126x over previous
//
#include <hip/hip_runtime.h>
#include <hip/hip_bf16.h>
#include <cstddef>

// Problem constants (fixed by reference)
#define N_USERS   100000
#define N_ITEMS   100000
#define N_NODES   200000
#define D         64
#define BATCH     2048
#define HIST      50
#define N_ITEMS_PAD 100096   // padded to multiple of 128 (block item-chunk)

#define BUCKET_SHIFT 9                       // 512 rows per bucket
#define N_BUCKETS ((N_NODES + 511) >> 9)     // 391
#define CHUNK 16384                          // edges per pass-A block

typedef __attribute__((ext_vector_type(8))) short short8;
typedef __attribute__((ext_vector_type(16))) float float16;

__device__ __forceinline__ ushort f2bf(float x) {  // fp32 -> bf16 RNE
    unsigned u = __float_as_uint(x);
    return (ushort)((u + 0x7FFF + ((u >> 16) & 1)) >> 16);
}
__device__ __forceinline__ unsigned char f2fp8(float x) {  // fp32 -> fp8 e4m3 (OCP), RNE+sat
    int p = __builtin_amdgcn_cvt_pk_fp8_f32(x, x, 0, false);
    return (unsigned char)(p & 0xFF);
}
__device__ __forceinline__ float fp82f(unsigned char u) {  // fp8 e4m3 -> fp32
    return __builtin_amdgcn_cvt_f32_fp8((int)u, 0);
}

// ---------------- CSR build ----------------
__global__ void k_hist(const int* __restrict__ adj_row, int* __restrict__ deg, int nedges) {
    int e = blockIdx.x * 256 + threadIdx.x;
    if (e < nedges) atomicAdd(&deg[adj_row[e]], 1);
}

// ---------------- init: w0 = fp8( 64 * x0 / sqrt(max(deg,1)) )  (z-space, scaled by 64) ----------------
__global__ void k_init(const float* __restrict__ user_emb, const float* __restrict__ item_emb,
                       const int* __restrict__ deg, unsigned char* __restrict__ w0) {
    int f = blockIdx.x * 256 + threadIdx.x;              // one 4-dim group
    if (f >= N_NODES * (D / 4)) return;
    int row = f >> 4;
    const float4* src = (row < N_USERS)
        ? ((const float4*)user_emb) + (size_t)row * 16 + (f & 15)
        : ((const float4*)item_emb) + (size_t)(row - (N_USERS - 1)) * 16 + (f & 15);
    float4 v = *src;
    int dg = deg[row]; if (dg < 1) dg = 1;
    float sc = 64.f * __frsqrt_rn((float)dg);
    uchar4 o;
    o.x = f2fp8(v.x * sc); o.y = f2fp8(v.y * sc);
    o.z = f2fp8(v.z * sc); o.w = f2fp8(v.w * sc);
    ((uchar4*)w0)[f] = o;
}

__global__ __launch_bounds__(256) void k_scan_block(const int* __restrict__ deg,
                                                    int* __restrict__ rowptr, int* __restrict__ bsums) {
    __shared__ int s[256];
    int t = threadIdx.x;
    int base = blockIdx.x * 1024 + t * 4;
    int d[4]; int tsum = 0;
#pragma unroll
    for (int k = 0; k < 4; ++k) { d[k] = (base + k < N_NODES) ? deg[base + k] : 0; tsum += d[k]; }
    s[t] = tsum; __syncthreads();
    for (int off = 1; off < 256; off <<= 1) {
        int v = (t >= off) ? s[t - off] : 0;
        __syncthreads();
        s[t] += v;
        __syncthreads();
    }
    int excl = s[t] - tsum;
    int run = excl;
#pragma unroll
    for (int k = 0; k < 4; ++k) { if (base + k < N_NODES) rowptr[base + k] = run; run += d[k]; }
    if (t == 255) bsums[blockIdx.x] = s[255];
}

__global__ __launch_bounds__(256) void k_scan_sums(int* __restrict__ bsums, int nb) {
    __shared__ int s[256];
    int t = threadIdx.x;
    int v0 = (t < nb) ? bsums[t] : 0;
    s[t] = v0; __syncthreads();
    for (int off = 1; off < 256; off <<= 1) {
        int v = (t >= off) ? s[t - off] : 0;
        __syncthreads();
        s[t] += v;
        __syncthreads();
    }
    if (t < nb) bsums[t] = s[t] - v0;   // exclusive
}

__global__ void k_scan_add(int* __restrict__ rowptr, const int* __restrict__ bsums, int nedges) {
    int i = blockIdx.x * 256 + threadIdx.x;
    if (i < N_NODES) rowptr[i] += bsums[i >> 10];
    if (i == 0) rowptr[N_NODES] = nedges;
}

// bucket arena cursors: gcursor[b] = rowptr[b*512]
__global__ void k_bucket_init(const int* __restrict__ rowptr, int* __restrict__ gcursor) {
    int b = blockIdx.x * 256 + threadIdx.x;
    if (b < N_BUCKETS) gcursor[b] = rowptr[b << BUCKET_SHIFT];
}

// ---------------- scatter pass A: bin edges into 391 row-buckets, LDS-aggregated ----------------
// staged record = (row&511)<<18 | col  (27 bits). Writes are contiguous runs per bucket per block.
__global__ __launch_bounds__(256) void k_scatter_a(const int* __restrict__ adj_row, const int* __restrict__ adj_col,
                                                   int* __restrict__ gcursor, int* __restrict__ staged, int nedges) {
    __shared__ int counts[N_BUCKETS];
    __shared__ int cursors[N_BUCKETS];
    int t = threadIdx.x;
    int base = blockIdx.x * CHUNK;
    for (int i = t; i < N_BUCKETS; i += 256) counts[i] = 0;
    __syncthreads();
    // phase 1: count
    for (int k = 0; k < CHUNK / 256; ++k) {
        int e = base + k * 256 + t;
        if (e < nedges) atomicAdd(&counts[adj_row[e] >> BUCKET_SHIFT], 1);
    }
    __syncthreads();
    // phase 2: reserve contiguous ranges in each bucket arena
    for (int b = t; b < N_BUCKETS; b += 256) {
        int c = counts[b];
        cursors[b] = (c > 0) ? atomicAdd(&gcursor[b], c) : 0;
    }
    __syncthreads();
    // phase 3: write packed records
    for (int k = 0; k < CHUNK / 256; ++k) {
        int e = base + k * 256 + t;
        if (e < nedges) {
            int r = adj_row[e];
            int b = r >> BUCKET_SHIFT;
            int p = atomicAdd(&cursors[b], 1);
            staged[p] = ((r & 511) << 18) | adj_col[e];
        }
    }
}

// ---------------- scatter pass B: one block per bucket; LDS row cursors; L2-local writes ----------------
__global__ __launch_bounds__(256) void k_scatter_b(const int* __restrict__ rowptr, const int* __restrict__ staged,
                                                   int* __restrict__ ecols) {
    __shared__ int cur[512];
    int b = blockIdx.x, t = threadIdx.x;
    int r0 = b << BUCKET_SHIFT;
    int r1 = r0 + 512; if (r1 > N_NODES) r1 = N_NODES;
    for (int j = t; j < r1 - r0; j += 256) cur[j] = rowptr[r0 + j];
    __syncthreads();
    int es = rowptr[r0], ee = rowptr[r1];
    for (int e = es + t; e < ee; e += 256) {
        int v = staged[e];
        int rwb = v >> 18;
        int col = v & 0x3FFFF;
        int pos = atomicAdd(&cur[rwb], 1);
        ecols[pos] = col << 6;     // byte offset into fp8 node rows
    }
}

// ---------------- propagate (fp8 z-space): w_out[r] = (1/deg_r) * sum w_in[c] ----------------
// one wave per row, lane = dim (1 byte/lane -> one 64B line per edge gather)
__global__ __launch_bounds__(256) void k_prop(const int* __restrict__ rowptr, const int* __restrict__ ecols,
                                              const unsigned char* __restrict__ x_in,
                                              unsigned char* __restrict__ x_out) {
    int w = blockIdx.x * 4 + (threadIdx.x >> 6);
    int lane = threadIdx.x & 63;
    int s = rowptr[w], e = rowptr[w + 1];
    float sum = 0.f;
    int p = s;
    for (; p + 8 <= e; p += 8) {
        int c[8];
#pragma unroll
        for (int j = 0; j < 8; ++j) c[j] = ecols[p + j];   // wave-uniform -> s_load
        float xv[8];
#pragma unroll
        for (int j = 0; j < 8; ++j) xv[j] = fp82f(x_in[c[j] + lane]);
#pragma unroll
        for (int j = 0; j < 8; ++j) sum += xv[j];
    }
    for (; p < e; ++p) sum += fp82f(x_in[ecols[p] + lane]);
    int cnt = e - s;
    float wv = (cnt > 0) ? sum / (float)cnt : 0.f;
    x_out[w * D + lane] = f2fp8(wv);
}

// ---------------- item latents: bf16( 0.25*item_emb + sqrt(deg)/256*(w1+w2+w3) ), zero-pad ----------------
__global__ void k_conv_items(const float* __restrict__ item_emb, const int* __restrict__ deg,
                             const unsigned char* __restrict__ w1, const unsigned char* __restrict__ w2,
                             const unsigned char* __restrict__ w3, ushort* __restrict__ item_bf) {
    int f = blockIdx.x * 256 + threadIdx.x;    // one 4-dim group
    if (f >= N_ITEMS_PAD * (D / 4)) return;
    int row = f >> 4, c4 = f & 15;
    ushort4 o;
    if (row < N_ITEMS) {
        int node = N_USERS + row;
        int dg = deg[node]; if (dg < 1) dg = 1;
        float s = sqrtf((float)dg) * (1.f / 256.f);    // sqrt(deg)/(64 scale * 4 avg)
        float4 e4 = ((const float4*)(item_emb + (size_t)(row + 1) * D))[c4];
        size_t n4 = (size_t)node * 16 + c4;
        uchar4 a = ((const uchar4*)w1)[n4];
        uchar4 b = ((const uchar4*)w2)[n4];
        uchar4 c = ((const uchar4*)w3)[n4];
        o.x = f2bf(0.25f * e4.x + s * (fp82f(a.x) + fp82f(b.x) + fp82f(c.x)));
        o.y = f2bf(0.25f * e4.y + s * (fp82f(a.y) + fp82f(b.y) + fp82f(c.y)));
        o.z = f2bf(0.25f * e4.z + s * (fp82f(a.z) + fp82f(b.z) + fp82f(c.z)));
        o.w = f2bf(0.25f * e4.w + s * (fp82f(a.w) + fp82f(b.w) + fp82f(c.w)));
    } else {
        o.x = o.y = o.z = o.w = 0;   // pad rows -> score 0 -> exp = 1 (subtract 96 in k_loss)
    }
    ((ushort4*)item_bf)[f] = o;
}

// ---------------- pred (bf16 copy) + label score ----------------
__global__ __launch_bounds__(256) void k_pred(const int* __restrict__ user_seqs, const int* __restrict__ his,
                                              const int* __restrict__ next_items,
                                              const float* __restrict__ user_emb, const float* __restrict__ item_emb,
                                              const int* __restrict__ deg,
                                              const unsigned char* __restrict__ w1, const unsigned char* __restrict__ w2,
                                              const unsigned char* __restrict__ w3,
                                              ushort* __restrict__ pred_bf, float* __restrict__ slabel) {
    int b = blockIdx.x * 4 + (threadIdx.x >> 6);
    int lane = threadIdx.x & 63;
    int u = user_seqs[b];
    float hsum = 0.f; int cnt = 0;
    for (int j = 0; j < HIST; ++j) {
        int it = his[b * HIST + j];
        cnt += (it != 0);
        hsum += item_emb[(size_t)it * D + lane];   // item_emb[0] is all-zero (pad)
    }
    int du = deg[u]; if (du < 1) du = 1;
    float su = sqrtf((float)du) * (1.f / 256.f);
    size_t ur = (size_t)u * D + lane;
    float ulat = 0.25f * user_emb[ur] + su * (fp82f(w1[ur]) + fp82f(w2[ur]) + fp82f(w3[ur]));
    float pv = ulat + hsum / (float)cnt;
    pred_bf[(size_t)b * D + lane] = f2bf(pv);
    int lab = next_items[b] - 1;
    int node = N_USERS + lab;
    int di = deg[node]; if (di < 1) di = 1;
    float si = sqrtf((float)di) * (1.f / 256.f);
    size_t nr = (size_t)node * D + lane;
    float ilat = 0.25f * item_emb[(size_t)(lab + 1) * D + lane]
               + si * (fp82f(w1[nr]) + fp82f(w2[nr]) + fp82f(w3[nr]));
    float tv = pv * ilat;
#pragma unroll
    for (int off = 32; off > 0; off >>= 1) tv += __shfl_down(tv, off);
    if (lane == 0) slabel[b] = tv;
}

// ---------------- MFMA scores + max-free sumexp ----------------
__global__ __launch_bounds__(256) void k_scores(const ushort* __restrict__ item_bf,
                                                const ushort* __restrict__ pred_bf,
                                                float* __restrict__ sumexp) {
    __shared__ float lds[4 * 2048];  // 4 waves x 2048 floats = 32 KB
    int t = threadIdx.x, wv = t >> 6, lane = t & 63;
    for (int i = t; i < 4 * 2048; i += 256) lds[i] = 0.f;
    __syncthreads();

    int item0 = blockIdx.x * 128 + wv * 32 + (lane & 31);
    int khalf = (lane >> 5) * 8;   // which 8-elem k-half this lane holds

    const ushort* ib = item_bf + (size_t)item0 * D + khalf;
    short8 afrag[4];
#pragma unroll
    for (int tt = 0; tt < 4; ++tt) afrag[tt] = *(const short8*)(ib + 16 * tt);

    float* myld = lds + wv * 2048;
    for (int mi = 0; mi < 64; ++mi) {
        int mtile = mi * 32;
        const ushort* pb = pred_bf + (size_t)(mtile + (lane & 31)) * D + khalf;
        short8 b0 = *(const short8*)(pb);
        short8 b1 = *(const short8*)(pb + 16);
        short8 b2 = *(const short8*)(pb + 32);
        short8 b3 = *(const short8*)(pb + 48);
        float16 c = {0.f};
        c = __builtin_amdgcn_mfma_f32_32x32x16_bf16(afrag[0], b0, c, 0, 0, 0);
        c = __builtin_amdgcn_mfma_f32_32x32x16_bf16(afrag[1], b1, c, 0, 0, 0);
        c = __builtin_amdgcn_mfma_f32_32x32x16_bf16(afrag[2], b2, c, 0, 0, 0);
        c = __builtin_amdgcn_mfma_f32_32x32x16_bf16(afrag[3], b3, c, 0, 0, 0);
        float part = 0.f;
#pragma unroll
        for (int r = 0; r < 16; ++r) part += __expf(c[r]);
        part += __shfl_down(part, 32);          // fold the two col-duplicate half-waves
        if (lane < 32) {
            float* p = myld + mtile + lane;     // wave-private, conflict-free
            *p += part;
        }
    }
    __syncthreads();
    for (int m = t; m < 2048; m += 256) {
        float v = lds[m] + lds[2048 + m] + lds[4096 + m] + lds[6144 + m];
        unsafeAtomicAdd(&sumexp[m], v);
    }
}

// ---------------- final loss reduce ----------------
__global__ __launch_bounds__(256) void k_loss(const float* __restrict__ sumexp, const float* __restrict__ slabel,
                                              float* __restrict__ out) {
    __shared__ float ws[4];
    int t = threadIdx.x;
    float v = 0.f;
    for (int i = t; i < BATCH; i += 256)
        v += __logf(sumexp[i] - 96.0f) - slabel[i];   // -96: padded items contribute exp(0)=1 each
#pragma unroll
    for (int off = 32; off > 0; off >>= 1) v += __shfl_down(v, off);
    if ((t & 63) == 0) ws[t >> 6] = v;
    __syncthreads();
    if (t == 0) out[0] = (ws[0] + ws[1] + ws[2] + ws[3]) * (1.f / (float)BATCH);
}

extern "C" void kernel_launch(void* const* d_in, const int* in_sizes, int n_in,
                              void* d_out, int out_size, void* d_ws, size_t ws_size,
                              hipStream_t stream) {
    const int*   user_seqs = (const int*)d_in[0];
    const int*   his       = (const int*)d_in[1];
    const int*   next_itm  = (const int*)d_in[2];
    const int*   adj_row   = (const int*)d_in[3];
    const int*   adj_col   = (const int*)d_in[4];
    const float* user_emb  = (const float*)d_in[6];
    const float* item_emb  = (const float*)d_in[7];
    float* out = (float*)d_out;
    int nedges = in_sizes[3];   // 12,800,000

    // Workspace layout (~170 MB)
    unsigned char* w0 = (unsigned char*)d_ws;              // 12.8 MB each
    unsigned char* w1 = w0 + (size_t)N_NODES * D;
    unsigned char* w2 = w1 + (size_t)N_NODES * D;
    unsigned char* w3 = w2 + (size_t)N_NODES * D;
    float*  slabel = (float*)(w3 + (size_t)N_NODES * D);   // 2,048
    float*  sumexp = slabel + BATCH;                       // 2,048   (zeroed)
    int*    deg    = (int*)(sumexp + BATCH);               // 200,000 (zeroed)
    int*    rowptr = deg + N_NODES;                        // 200,002
    int*    bsums  = rowptr + (N_NODES + 2);               // 256
    int*    gcursor= bsums + 256;                          // 392
    int*    staged = gcursor + 392;                        // 12.8M ints (51.2 MB)
    int*    ecols  = staged + (size_t)nedges;              // 12.8M ints (51.2 MB)
    ushort* item_bf = (ushort*)(ecols + (size_t)nedges);   // 100096*64 ushort
    ushort* pred_bf = item_bf + (size_t)N_ITEMS_PAD * D;   // 131072 ushort

    // zero sumexp + deg in one shot (contiguous)
    hipError_t _e = hipMemsetAsync(sumexp, 0, (size_t)(BATCH + N_NODES) * sizeof(int), stream);
    (void)_e;

    k_hist<<<(nedges + 255) / 256, 256, 0, stream>>>(adj_row, deg, nedges);
    k_init<<<(N_NODES * (D / 4) + 255) / 256, 256, 0, stream>>>(user_emb, item_emb, deg, w0);

    int nsb = (N_NODES + 1023) / 1024;  // 196
    k_scan_block<<<nsb, 256, 0, stream>>>(deg, rowptr, bsums);
    k_scan_sums<<<1, 256, 0, stream>>>(bsums, nsb);
    k_scan_add<<<(N_NODES + 255) / 256, 256, 0, stream>>>(rowptr, bsums, nedges);
    k_bucket_init<<<2, 256, 0, stream>>>(rowptr, gcursor);

    k_scatter_a<<<(nedges + CHUNK - 1) / CHUNK, 256, 0, stream>>>(adj_row, adj_col, gcursor, staged, nedges);
    k_scatter_b<<<N_BUCKETS, 256, 0, stream>>>(rowptr, staged, ecols);

    k_prop<<<N_NODES / 4, 256, 0, stream>>>(rowptr, ecols, w0, w1);
    k_prop<<<N_NODES / 4, 256, 0, stream>>>(rowptr, ecols, w1, w2);
    k_prop<<<N_NODES / 4, 256, 0, stream>>>(rowptr, ecols, w2, w3);

    k_conv_items<<<(N_ITEMS_PAD * (D / 4) + 255) / 256, 256, 0, stream>>>(item_emb, deg, w1, w2, w3, item_bf);
    k_pred<<<BATCH / 4, 256, 0, stream>>>(user_seqs, his, next_itm, user_emb, item_emb, deg,
                                          w1, w2, w3, pred_bf, slabel);

    k_scores<<<N_ITEMS_PAD / 128, 256, 0, stream>>>(item_bf, pred_bf, sumexp);

    k_loss<<<1, 256, 0, stream>>>(sumexp, slabel, out);
}

// Round 7
// 947.340 us; speedup vs baseline: 1.6171x; 1.2320x over previous
//
#include <hip/hip_runtime.h>
#include <hip/hip_bf16.h>
#include <cstddef>

// Problem constants (fixed by reference)
#define N_USERS   100000
#define N_ITEMS   100000
#define N_NODES   200000
#define D         64
#define BATCH     2048
#define HIST      50
#define N_ITEMS_PAD 100096   // padded to multiple of 128 (block item-chunk)

#define BUCKET_SHIFT 9                       // 512 rows per bucket
#define N_BUCKETS ((N_NODES + 511) >> 9)     // 391
#define CHUNK 16384                          // edges per binning block

typedef __attribute__((ext_vector_type(8))) short short8;
typedef __attribute__((ext_vector_type(16))) float float16;

__device__ __forceinline__ ushort f2bf(float x) {  // fp32 -> bf16 RNE
    unsigned u = __float_as_uint(x);
    return (ushort)((u + 0x7FFF + ((u >> 16) & 1)) >> 16);
}
__device__ __forceinline__ unsigned char f2fp8(float x) {  // fp32 -> fp8 e4m3 (OCP), RNE+sat
    int p = __builtin_amdgcn_cvt_pk_fp8_f32(x, x, 0, false);
    return (unsigned char)(p & 0xFF);
}
__device__ __forceinline__ float fp82f(unsigned char u) {  // fp8 e4m3 -> fp32
    return __builtin_amdgcn_cvt_f32_fp8((int)u, 0);
}

// ---------------- bucket histogram: 391 counters, LDS-aggregated ----------------
__global__ __launch_bounds__(256) void k_bucket_hist(const int* __restrict__ adj_row,
                                                     int* __restrict__ btot, int nedges) {
    __shared__ int counts[N_BUCKETS];
    int t = threadIdx.x;
    int base = blockIdx.x * CHUNK;
    for (int i = t; i < N_BUCKETS; i += 256) counts[i] = 0;
    __syncthreads();
    for (int k = 0; k < CHUNK / 256; ++k) {
        int e = base + k * 256 + t;
        if (e < nedges) atomicAdd(&counts[adj_row[e] >> BUCKET_SHIFT], 1);
    }
    __syncthreads();
    for (int i = t; i < N_BUCKETS; i += 256) {
        int c = counts[i];
        if (c) atomicAdd(&btot[i], c);
    }
}

// ---------------- scan 391 bucket totals -> bases; seed arena cursors ----------------
__global__ __launch_bounds__(256) void k_bucket_scan(const int* __restrict__ btot,
                                                     int* __restrict__ bbase, int* __restrict__ gcursor,
                                                     int nedges) {
    __shared__ int s[256];
    int t = threadIdx.x;
    int v0 = (2 * t     < N_BUCKETS) ? btot[2 * t]     : 0;
    int v1 = (2 * t + 1 < N_BUCKETS) ? btot[2 * t + 1] : 0;
    int sum = v0 + v1;
    s[t] = sum; __syncthreads();
    for (int off = 1; off < 256; off <<= 1) {
        int v = (t >= off) ? s[t - off] : 0;
        __syncthreads();
        s[t] += v;
        __syncthreads();
    }
    int excl = s[t] - sum;
    if (2 * t < N_BUCKETS)     { bbase[2 * t]     = excl;      gcursor[2 * t]     = excl; }
    if (2 * t + 1 < N_BUCKETS) { bbase[2 * t + 1] = excl + v0; gcursor[2 * t + 1] = excl + v0; }
    if (t == 0) bbase[N_BUCKETS] = nedges;
}

// ---------------- scatter pass A: bin edges into bucket arenas (contiguous runs) ----------------
// staged record = (row&511)<<18 | col  (27 bits)
__global__ __launch_bounds__(256) void k_scatter_a(const int* __restrict__ adj_row, const int* __restrict__ adj_col,
                                                   int* __restrict__ gcursor, int* __restrict__ staged, int nedges) {
    __shared__ int counts[N_BUCKETS];
    __shared__ int cursors[N_BUCKETS];
    int t = threadIdx.x;
    int base = blockIdx.x * CHUNK;
    for (int i = t; i < N_BUCKETS; i += 256) counts[i] = 0;
    __syncthreads();
    for (int k = 0; k < CHUNK / 256; ++k) {
        int e = base + k * 256 + t;
        if (e < nedges) atomicAdd(&counts[adj_row[e] >> BUCKET_SHIFT], 1);
    }
    __syncthreads();
    for (int b = t; b < N_BUCKETS; b += 256) {
        int c = counts[b];
        cursors[b] = (c > 0) ? atomicAdd(&gcursor[b], c) : 0;
    }
    __syncthreads();
    for (int k = 0; k < CHUNK / 256; ++k) {
        int e = base + k * 256 + t;
        if (e < nedges) {
            int r = adj_row[e];
            int b = r >> BUCKET_SHIFT;
            int p = atomicAdd(&cursors[b], 1);
            staged[p] = ((r & 511) << 18) | adj_col[e];
        }
    }
}

// ---------------- scatter pass B: per bucket, build rowptr+deg via LDS scan, place edges ----------------
__global__ __launch_bounds__(256) void k_scatter_b(const int* __restrict__ bbase, const int* __restrict__ staged,
                                                   int* __restrict__ ecols, int* __restrict__ rowptr,
                                                   int* __restrict__ deg) {
    __shared__ int cnt[512];
    __shared__ int ts[256];
    __shared__ int cur[512];
    int b = blockIdx.x, t = threadIdx.x;
    cnt[t] = 0; cnt[t + 256] = 0;
    __syncthreads();
    int es = bbase[b], ee = bbase[b + 1];
    for (int e = es + t; e < ee; e += 256) atomicAdd(&cnt[staged[e] >> 18], 1);
    __syncthreads();
    int c0 = cnt[2 * t], c1 = cnt[2 * t + 1];
    int sum = c0 + c1;
    ts[t] = sum; __syncthreads();
    for (int off = 1; off < 256; off <<= 1) {
        int v = (t >= off) ? ts[t - off] : 0;
        __syncthreads();
        ts[t] += v;
        __syncthreads();
    }
    int excl = ts[t] - sum;
    int r0 = b << BUCKET_SHIFT;
    int g0 = es + excl, g1 = es + excl + c0;
    if (r0 + 2 * t < N_NODES)     { rowptr[r0 + 2 * t]     = g0; deg[r0 + 2 * t]     = c0; }
    if (r0 + 2 * t + 1 < N_NODES) { rowptr[r0 + 2 * t + 1] = g1; deg[r0 + 2 * t + 1] = c1; }
    cur[2 * t] = g0; cur[2 * t + 1] = g1;
    if (b == N_BUCKETS - 1 && t == 0) rowptr[N_NODES] = ee;
    __syncthreads();
    for (int e = es + t; e < ee; e += 256) {
        int v = staged[e];
        int pos = atomicAdd(&cur[v >> 18], 1);
        ecols[pos] = (v & 0x3FFFF) << 6;   // byte offset into fp8 node rows
    }
}

// ---------------- init: w0 = fp8( 64 * x0 / sqrt(max(deg,1)) )  (z-space, scaled by 64) ----------------
__global__ void k_init(const float* __restrict__ user_emb, const float* __restrict__ item_emb,
                       const int* __restrict__ deg, unsigned char* __restrict__ w0) {
    int f = blockIdx.x * 256 + threadIdx.x;              // one 4-dim group
    if (f >= N_NODES * (D / 4)) return;
    int row = f >> 4;
    const float4* src = (row < N_USERS)
        ? ((const float4*)user_emb) + (size_t)row * 16 + (f & 15)
        : ((const float4*)item_emb) + (size_t)(row - (N_USERS - 1)) * 16 + (f & 15);
    float4 v = *src;
    int dg = deg[row]; if (dg < 1) dg = 1;
    float sc = 64.f * __frsqrt_rn((float)dg);
    uchar4 o;
    o.x = f2fp8(v.x * sc); o.y = f2fp8(v.y * sc);
    o.z = f2fp8(v.z * sc); o.w = f2fp8(v.w * sc);
    ((uchar4*)w0)[f] = o;
}

// ---------------- propagate (fp8 z-space): w_out[r] = (1/deg_r) * sum w_in[c] ----------------
// one wave per row, lane = dim (1 byte/lane -> one 64B line per edge gather)
__global__ __launch_bounds__(256) void k_prop(const int* __restrict__ rowptr, const int* __restrict__ ecols,
                                              const unsigned char* __restrict__ x_in,
                                              unsigned char* __restrict__ x_out) {
    int w = blockIdx.x * 4 + (threadIdx.x >> 6);
    int lane = threadIdx.x & 63;
    int s = rowptr[w], e = rowptr[w + 1];
    float sum = 0.f;
    int p = s;
    for (; p + 8 <= e; p += 8) {
        int c[8];
#pragma unroll
        for (int j = 0; j < 8; ++j) c[j] = ecols[p + j];   // wave-uniform -> s_load
        float xv[8];
#pragma unroll
        for (int j = 0; j < 8; ++j) xv[j] = fp82f(x_in[c[j] + lane]);
#pragma unroll
        for (int j = 0; j < 8; ++j) sum += xv[j];
    }
    for (; p < e; ++p) sum += fp82f(x_in[ecols[p] + lane]);
    int cnt = e - s;
    float wv = (cnt > 0) ? sum / (float)cnt : 0.f;
    x_out[w * D + lane] = f2fp8(wv);
}

// ---------------- item latents: bf16( 0.25*item_emb + sqrt(deg)/256*(w1+w2+w3) ), zero-pad ----------------
__global__ void k_conv_items(const float* __restrict__ item_emb, const int* __restrict__ deg,
                             const unsigned char* __restrict__ w1, const unsigned char* __restrict__ w2,
                             const unsigned char* __restrict__ w3, ushort* __restrict__ item_bf) {
    int f = blockIdx.x * 256 + threadIdx.x;    // one 4-dim group
    if (f >= N_ITEMS_PAD * (D / 4)) return;
    int row = f >> 4, c4 = f & 15;
    ushort4 o;
    if (row < N_ITEMS) {
        int node = N_USERS + row;
        int dg = deg[node]; if (dg < 1) dg = 1;
        float s = sqrtf((float)dg) * (1.f / 256.f);    // sqrt(deg)/(64 scale * 4 avg)
        float4 e4 = ((const float4*)(item_emb + (size_t)(row + 1) * D))[c4];
        size_t n4 = (size_t)node * 16 + c4;
        uchar4 a = ((const uchar4*)w1)[n4];
        uchar4 b = ((const uchar4*)w2)[n4];
        uchar4 c = ((const uchar4*)w3)[n4];
        o.x = f2bf(0.25f * e4.x + s * (fp82f(a.x) + fp82f(b.x) + fp82f(c.x)));
        o.y = f2bf(0.25f * e4.y + s * (fp82f(a.y) + fp82f(b.y) + fp82f(c.y)));
        o.z = f2bf(0.25f * e4.z + s * (fp82f(a.z) + fp82f(b.z) + fp82f(c.z)));
        o.w = f2bf(0.25f * e4.w + s * (fp82f(a.w) + fp82f(b.w) + fp82f(c.w)));
    } else {
        o.x = o.y = o.z = o.w = 0;   // pad rows -> score 0 -> exp = 1 (subtract 96 in k_loss)
    }
    ((ushort4*)item_bf)[f] = o;
}

// ---------------- pred (bf16 copy) + label score ----------------
__global__ __launch_bounds__(256) void k_pred(const int* __restrict__ user_seqs, const int* __restrict__ his,
                                              const int* __restrict__ next_items,
                                              const float* __restrict__ user_emb, const float* __restrict__ item_emb,
                                              const int* __restrict__ deg,
                                              const unsigned char* __restrict__ w1, const unsigned char* __restrict__ w2,
                                              const unsigned char* __restrict__ w3,
                                              ushort* __restrict__ pred_bf, float* __restrict__ slabel) {
    int b = blockIdx.x * 4 + (threadIdx.x >> 6);
    int lane = threadIdx.x & 63;
    int u = user_seqs[b];
    float hsum = 0.f; int cnt = 0;
    for (int j = 0; j < HIST; ++j) {
        int it = his[b * HIST + j];
        cnt += (it != 0);
        hsum += item_emb[(size_t)it * D + lane];   // item_emb[0] is all-zero (pad)
    }
    int du = deg[u]; if (du < 1) du = 1;
    float su = sqrtf((float)du) * (1.f / 256.f);
    size_t ur = (size_t)u * D + lane;
    float ulat = 0.25f * user_emb[ur] + su * (fp82f(w1[ur]) + fp82f(w2[ur]) + fp82f(w3[ur]));
    float pv = ulat + hsum / (float)cnt;
    pred_bf[(size_t)b * D + lane] = f2bf(pv);
    int lab = next_items[b] - 1;
    int node = N_USERS + lab;
    int di = deg[node]; if (di < 1) di = 1;
    float si = sqrtf((float)di) * (1.f / 256.f);
    size_t nr = (size_t)node * D + lane;
    float ilat = 0.25f * item_emb[(size_t)(lab + 1) * D + lane]
               + si * (fp82f(w1[nr]) + fp82f(w2[nr]) + fp82f(w3[nr]));
    float tv = pv * ilat;
#pragma unroll
    for (int off = 32; off > 0; off >>= 1) tv += __shfl_down(tv, off);
    if (lane == 0) slabel[b] = tv;
}

// ---------------- MFMA scores + max-free sumexp ----------------
__global__ __launch_bounds__(256) void k_scores(const ushort* __restrict__ item_bf,
                                                const ushort* __restrict__ pred_bf,
                                                float* __restrict__ sumexp) {
    __shared__ float lds[4 * 2048];  // 4 waves x 2048 floats = 32 KB
    int t = threadIdx.x, wv = t >> 6, lane = t & 63;
    for (int i = t; i < 4 * 2048; i += 256) lds[i] = 0.f;
    __syncthreads();

    int item0 = blockIdx.x * 128 + wv * 32 + (lane & 31);
    int khalf = (lane >> 5) * 8;   // which 8-elem k-half this lane holds

    const ushort* ib = item_bf + (size_t)item0 * D + khalf;
    short8 afrag[4];
#pragma unroll
    for (int tt = 0; tt < 4; ++tt) afrag[tt] = *(const short8*)(ib + 16 * tt);

    float* myld = lds + wv * 2048;
    for (int mi = 0; mi < 64; ++mi) {
        int mtile = mi * 32;
        const ushort* pb = pred_bf + (size_t)(mtile + (lane & 31)) * D + khalf;
        short8 b0 = *(const short8*)(pb);
        short8 b1 = *(const short8*)(pb + 16);
        short8 b2 = *(const short8*)(pb + 32);
        short8 b3 = *(const short8*)(pb + 48);
        float16 c = {0.f};
        c = __builtin_amdgcn_mfma_f32_32x32x16_bf16(afrag[0], b0, c, 0, 0, 0);
        c = __builtin_amdgcn_mfma_f32_32x32x16_bf16(afrag[1], b1, c, 0, 0, 0);
        c = __builtin_amdgcn_mfma_f32_32x32x16_bf16(afrag[2], b2, c, 0, 0, 0);
        c = __builtin_amdgcn_mfma_f32_32x32x16_bf16(afrag[3], b3, c, 0, 0, 0);
        float part = 0.f;
#pragma unroll
        for (int r = 0; r < 16; ++r) part += __expf(c[r]);
        part += __shfl_down(part, 32);          // fold the two col-duplicate half-waves
        if (lane < 32) {
            float* p = myld + mtile + lane;     // wave-private, conflict-free
            *p += part;
        }
    }
    __syncthreads();
    for (int m = t; m < 2048; m += 256) {
        float v = lds[m] + lds[2048 + m] + lds[4096 + m] + lds[6144 + m];
        unsafeAtomicAdd(&sumexp[m], v);
    }
}

// ---------------- final loss reduce ----------------
__global__ __launch_bounds__(256) void k_loss(const float* __restrict__ sumexp, const float* __restrict__ slabel,
                                              float* __restrict__ out) {
    __shared__ float ws[4];
    int t = threadIdx.x;
    float v = 0.f;
    for (int i = t; i < BATCH; i += 256)
        v += __logf(sumexp[i] - 96.0f) - slabel[i];   // -96: padded items contribute exp(0)=1 each
#pragma unroll
    for (int off = 32; off > 0; off >>= 1) v += __shfl_down(v, off);
    if ((t & 63) == 0) ws[t >> 6] = v;
    __syncthreads();
    if (t == 0) out[0] = (ws[0] + ws[1] + ws[2] + ws[3]) * (1.f / (float)BATCH);
}

extern "C" void kernel_launch(void* const* d_in, const int* in_sizes, int n_in,
                              void* d_out, int out_size, void* d_ws, size_t ws_size,
                              hipStream_t stream) {
    const int*   user_seqs = (const int*)d_in[0];
    const int*   his       = (const int*)d_in[1];
    const int*   next_itm  = (const int*)d_in[2];
    const int*   adj_row   = (const int*)d_in[3];
    const int*   adj_col   = (const int*)d_in[4];
    const float* user_emb  = (const float*)d_in[6];
    const float* item_emb  = (const float*)d_in[7];
    float* out = (float*)d_out;
    int nedges = in_sizes[3];   // 12,800,000

    // Workspace layout (~170 MB)
    unsigned char* w0 = (unsigned char*)d_ws;              // 12.8 MB each
    unsigned char* w1 = w0 + (size_t)N_NODES * D;
    unsigned char* w2 = w1 + (size_t)N_NODES * D;
    unsigned char* w3 = w2 + (size_t)N_NODES * D;
    float*  slabel = (float*)(w3 + (size_t)N_NODES * D);   // 2,048
    float*  sumexp = slabel + BATCH;                       // 2,048   (zeroed)
    int*    btot   = (int*)(sumexp + BATCH);               // 392     (zeroed)
    int*    bbase  = btot + 392;                           // 392
    int*    gcursor= bbase + 392;                          // 392
    int*    rowptr = gcursor + 392;                        // 200,002
    int*    deg    = rowptr + (N_NODES + 2);               // 200,000
    int*    staged = deg + N_NODES;                        // 12.8M ints (51.2 MB)
    int*    ecols  = staged + (size_t)nedges;              // 12.8M ints (51.2 MB)
    ushort* item_bf = (ushort*)(ecols + (size_t)nedges);   // 100096*64 ushort
    ushort* pred_bf = item_bf + (size_t)N_ITEMS_PAD * D;   // 131072 ushort

    // zero sumexp + btot in one shot (contiguous)
    hipError_t _e = hipMemsetAsync(sumexp, 0, (size_t)(BATCH + 392) * sizeof(int), stream);
    (void)_e;

    int nchunks = (nedges + CHUNK - 1) / CHUNK;
    k_bucket_hist<<<nchunks, 256, 0, stream>>>(adj_row, btot, nedges);
    k_bucket_scan<<<1, 256, 0, stream>>>(btot, bbase, gcursor, nedges);
    k_scatter_a<<<nchunks, 256, 0, stream>>>(adj_row, adj_col, gcursor, staged, nedges);
    k_scatter_b<<<N_BUCKETS, 256, 0, stream>>>(bbase, staged, ecols, rowptr, deg);

    k_init<<<(N_NODES * (D / 4) + 255) / 256, 256, 0, stream>>>(user_emb, item_emb, deg, w0);

    k_prop<<<N_NODES / 4, 256, 0, stream>>>(rowptr, ecols, w0, w1);
    k_prop<<<N_NODES / 4, 256, 0, stream>>>(rowptr, ecols, w1, w2);
    k_prop<<<N_NODES / 4, 256, 0, stream>>>(rowptr, ecols, w2, w3);

    k_conv_items<<<(N_ITEMS_PAD * (D / 4) + 255) / 256, 256, 0, stream>>>(item_emb, deg, w1, w2, w3, item_bf);
    k_pred<<<BATCH / 4, 256, 0, stream>>>(user_seqs, his, next_itm, user_emb, item_emb, deg,
                                          w1, w2, w3, pred_bf, slabel);

    k_scores<<<N_ITEMS_PAD / 128, 256, 0, stream>>>(item_bf, pred_bf, sumexp);

    k_loss<<<1, 256, 0, stream>>>(sumexp, slabel, out);
}

// Round 8
// 790.718 us; speedup vs baseline: 1.9374x; 1.1981x over previous
//
#include <hip/hip_runtime.h>
#include <hip/hip_bf16.h>
#include <cstddef>

// Problem constants (fixed by reference)
#define N_USERS   100000
#define N_ITEMS   100000
#define N_NODES   200000
#define D         64
#define BATCH     2048
#define HIST      50
#define N_ITEMS_PAD 100096   // padded to multiple of 128 (block item-chunk)

#define BUCKET_SHIFT 9                       // 512 rows per bucket
#define N_BUCKETS ((N_NODES + 511) >> 9)     // 391
#define CHUNK 16384                          // edges per binning block

typedef __attribute__((ext_vector_type(8))) short short8;
typedef __attribute__((ext_vector_type(16))) float float16;

__device__ __forceinline__ ushort f2bf(float x) {  // fp32 -> bf16 RNE
    unsigned u = __float_as_uint(x);
    return (ushort)((u + 0x7FFF + ((u >> 16) & 1)) >> 16);
}
__device__ __forceinline__ unsigned char f2fp8(float x) {  // fp32 -> fp8 e4m3 (OCP), RNE+sat
    int p = __builtin_amdgcn_cvt_pk_fp8_f32(x, x, 0, false);
    return (unsigned char)(p & 0xFF);
}
__device__ __forceinline__ float fp82f(unsigned char u) {  // fp8 e4m3 -> fp32
    return __builtin_amdgcn_cvt_f32_fp8((int)u, 0);
}

// ---------------- bucket histogram: 391 counters, LDS-aggregated ----------------
__global__ __launch_bounds__(256) void k_bucket_hist(const int* __restrict__ adj_row,
                                                     int* __restrict__ btot, int nedges) {
    __shared__ int counts[N_BUCKETS];
    int t = threadIdx.x;
    int base = blockIdx.x * CHUNK;
    for (int i = t; i < N_BUCKETS; i += 256) counts[i] = 0;
    __syncthreads();
    for (int k = 0; k < CHUNK / 256; ++k) {
        int e = base + k * 256 + t;
        if (e < nedges) atomicAdd(&counts[adj_row[e] >> BUCKET_SHIFT], 1);
    }
    __syncthreads();
    for (int i = t; i < N_BUCKETS; i += 256) {
        int c = counts[i];
        if (c) atomicAdd(&btot[i], c);
    }
}

// ---------------- scan 391 bucket totals -> bases; seed arena cursors ----------------
__global__ __launch_bounds__(256) void k_bucket_scan(const int* __restrict__ btot,
                                                     int* __restrict__ bbase, int* __restrict__ gcursor,
                                                     int nedges) {
    __shared__ int s[256];
    int t = threadIdx.x;
    int v0 = (2 * t     < N_BUCKETS) ? btot[2 * t]     : 0;
    int v1 = (2 * t + 1 < N_BUCKETS) ? btot[2 * t + 1] : 0;
    int sum = v0 + v1;
    s[t] = sum; __syncthreads();
    for (int off = 1; off < 256; off <<= 1) {
        int v = (t >= off) ? s[t - off] : 0;
        __syncthreads();
        s[t] += v;
        __syncthreads();
    }
    int excl = s[t] - sum;
    if (2 * t < N_BUCKETS)     { bbase[2 * t]     = excl;      gcursor[2 * t]     = excl; }
    if (2 * t + 1 < N_BUCKETS) { bbase[2 * t + 1] = excl + v0; gcursor[2 * t + 1] = excl + v0; }
    if (t == 0) bbase[N_BUCKETS] = nedges;
}

// ---------------- scatter pass A: bin edges into bucket arenas (contiguous runs) ----------------
// staged record = (row&511)<<18 | col  (27 bits)
__global__ __launch_bounds__(256) void k_scatter_a(const int* __restrict__ adj_row, const int* __restrict__ adj_col,
                                                   int* __restrict__ gcursor, int* __restrict__ staged, int nedges) {
    __shared__ int counts[N_BUCKETS];
    __shared__ int cursors[N_BUCKETS];
    int t = threadIdx.x;
    int base = blockIdx.x * CHUNK;
    for (int i = t; i < N_BUCKETS; i += 256) counts[i] = 0;
    __syncthreads();
    for (int k = 0; k < CHUNK / 256; ++k) {
        int e = base + k * 256 + t;
        if (e < nedges) atomicAdd(&counts[adj_row[e] >> BUCKET_SHIFT], 1);
    }
    __syncthreads();
    for (int b = t; b < N_BUCKETS; b += 256) {
        int c = counts[b];
        cursors[b] = (c > 0) ? atomicAdd(&gcursor[b], c) : 0;
    }
    __syncthreads();
    for (int k = 0; k < CHUNK / 256; ++k) {
        int e = base + k * 256 + t;
        if (e < nedges) {
            int r = adj_row[e];
            int b = r >> BUCKET_SHIFT;
            int p = atomicAdd(&cursors[b], 1);
            staged[p] = ((r & 511) << 18) | adj_col[e];
        }
    }
}

// ---------------- scatter pass B: per bucket, build rowptr+deg via LDS scan, place edges ----------------
__global__ __launch_bounds__(256) void k_scatter_b(const int* __restrict__ bbase, const int* __restrict__ staged,
                                                   int* __restrict__ ecols, int* __restrict__ rowptr,
                                                   int* __restrict__ deg) {
    __shared__ int cnt[512];
    __shared__ int ts[256];
    __shared__ int cur[512];
    int b = blockIdx.x, t = threadIdx.x;
    cnt[t] = 0; cnt[t + 256] = 0;
    __syncthreads();
    int es = bbase[b], ee = bbase[b + 1];
    for (int e = es + t; e < ee; e += 256) atomicAdd(&cnt[staged[e] >> 18], 1);
    __syncthreads();
    int c0 = cnt[2 * t], c1 = cnt[2 * t + 1];
    int sum = c0 + c1;
    ts[t] = sum; __syncthreads();
    for (int off = 1; off < 256; off <<= 1) {
        int v = (t >= off) ? ts[t - off] : 0;
        __syncthreads();
        ts[t] += v;
        __syncthreads();
    }
    int excl = ts[t] - sum;
    int r0 = b << BUCKET_SHIFT;
    int g0 = es + excl, g1 = es + excl + c0;
    if (r0 + 2 * t < N_NODES)     { rowptr[r0 + 2 * t]     = g0; deg[r0 + 2 * t]     = c0; }
    if (r0 + 2 * t + 1 < N_NODES) { rowptr[r0 + 2 * t + 1] = g1; deg[r0 + 2 * t + 1] = c1; }
    cur[2 * t] = g0; cur[2 * t + 1] = g1;
    if (b == N_BUCKETS - 1 && t == 0) rowptr[N_NODES] = ee;
    __syncthreads();
    for (int e = es + t; e < ee; e += 256) {
        int v = staged[e];
        int pos = atomicAdd(&cur[v >> 18], 1);
        ecols[pos] = (v & 0x3FFFF) << 6;   // byte offset into fp8 node rows
    }
}

// ---------------- init: w0 = fp8( 64 * x0 / sqrt(max(deg,1)) )  (z-space, scaled by 64) ----------------
__global__ void k_init(const float* __restrict__ user_emb, const float* __restrict__ item_emb,
                       const int* __restrict__ deg, unsigned char* __restrict__ w0) {
    int f = blockIdx.x * 256 + threadIdx.x;              // one 4-dim group
    if (f >= N_NODES * (D / 4)) return;
    int row = f >> 4;
    const float4* src = (row < N_USERS)
        ? ((const float4*)user_emb) + (size_t)row * 16 + (f & 15)
        : ((const float4*)item_emb) + (size_t)(row - (N_USERS - 1)) * 16 + (f & 15);
    float4 v = *src;
    int dg = deg[row]; if (dg < 1) dg = 1;
    float sc = 64.f * __frsqrt_rn((float)dg);
    uchar4 o;
    o.x = f2fp8(v.x * sc); o.y = f2fp8(v.y * sc);
    o.z = f2fp8(v.z * sc); o.w = f2fp8(v.w * sc);
    ((uchar4*)w0)[f] = o;
}

// ---------------- propagate (fp8 z-space): w_out[r] = (1/deg_r) * sum w_in[c] ----------------
// lane layout: slot = lane>>4 picks one of 4 edges, d4 = (lane&15)*4 picks 4 dims.
// One dword gather per lane covers 4 edges x 64 dims per wave-instruction.
__global__ __launch_bounds__(256) void k_prop(const int* __restrict__ rowptr, const int* __restrict__ ecols,
                                              const unsigned char* __restrict__ x_in,
                                              unsigned char* __restrict__ x_out) {
    int w = blockIdx.x * 4 + (threadIdx.x >> 6);
    int lane = threadIdx.x & 63;
    int slot = lane >> 4;
    int d4 = (lane & 15) * 4;
    const unsigned char* xb = x_in + d4;    // loop-invariant base for this lane's dims
    int s = rowptr[w], e = rowptr[w + 1];
    float ax = 0.f, ay = 0.f, az = 0.f, aw = 0.f;
    int p = s;
    for (; p + 16 <= e; p += 16) {
        int c0 = ecols[p + slot];
        int c1 = ecols[p + 4 + slot];
        int c2 = ecols[p + 8 + slot];
        int c3 = ecols[p + 12 + slot];
        unsigned b0 = *(const unsigned*)(xb + c0);
        unsigned b1 = *(const unsigned*)(xb + c1);
        unsigned b2 = *(const unsigned*)(xb + c2);
        unsigned b3 = *(const unsigned*)(xb + c3);
        ax += __builtin_amdgcn_cvt_f32_fp8((int)b0, 0);
        ay += __builtin_amdgcn_cvt_f32_fp8((int)b0, 1);
        az += __builtin_amdgcn_cvt_f32_fp8((int)b0, 2);
        aw += __builtin_amdgcn_cvt_f32_fp8((int)b0, 3);
        ax += __builtin_amdgcn_cvt_f32_fp8((int)b1, 0);
        ay += __builtin_amdgcn_cvt_f32_fp8((int)b1, 1);
        az += __builtin_amdgcn_cvt_f32_fp8((int)b1, 2);
        aw += __builtin_amdgcn_cvt_f32_fp8((int)b1, 3);
        ax += __builtin_amdgcn_cvt_f32_fp8((int)b2, 0);
        ay += __builtin_amdgcn_cvt_f32_fp8((int)b2, 1);
        az += __builtin_amdgcn_cvt_f32_fp8((int)b2, 2);
        aw += __builtin_amdgcn_cvt_f32_fp8((int)b2, 3);
        ax += __builtin_amdgcn_cvt_f32_fp8((int)b3, 0);
        ay += __builtin_amdgcn_cvt_f32_fp8((int)b3, 1);
        az += __builtin_amdgcn_cvt_f32_fp8((int)b3, 2);
        aw += __builtin_amdgcn_cvt_f32_fp8((int)b3, 3);
    }
    for (; p < e; p += 4) {
        int rem = e - p;                       // >= 1
        int sl = (slot < rem) ? slot : 0;
        int col = ecols[p + sl];
        unsigned b = *(const unsigned*)(xb + col);
        if (slot < rem) {
            ax += __builtin_amdgcn_cvt_f32_fp8((int)b, 0);
            ay += __builtin_amdgcn_cvt_f32_fp8((int)b, 1);
            az += __builtin_amdgcn_cvt_f32_fp8((int)b, 2);
            aw += __builtin_amdgcn_cvt_f32_fp8((int)b, 3);
        }
    }
    // cross-slot reduce: lanes L, L+16, L+32, L+48 hold same dims, different edges
    ax += __shfl_down(ax, 32); ay += __shfl_down(ay, 32);
    az += __shfl_down(az, 32); aw += __shfl_down(aw, 32);
    ax += __shfl_down(ax, 16); ay += __shfl_down(ay, 16);
    az += __shfl_down(az, 16); aw += __shfl_down(aw, 16);
    if (lane < 16) {
        int cnt = e - s;
        float inv = (cnt > 0) ? 1.f / (float)cnt : 0.f;
        uchar4 o;
        o.x = f2fp8(ax * inv); o.y = f2fp8(ay * inv);
        o.z = f2fp8(az * inv); o.w = f2fp8(aw * inv);
        *(uchar4*)(x_out + (size_t)w * D + d4) = o;
    }
}

// ---------------- item latents: bf16( 0.25*item_emb + sqrt(deg)/256*(w1+w2+w3) ), zero-pad ----------------
__global__ void k_conv_items(const float* __restrict__ item_emb, const int* __restrict__ deg,
                             const unsigned char* __restrict__ w1, const unsigned char* __restrict__ w2,
                             const unsigned char* __restrict__ w3, ushort* __restrict__ item_bf) {
    int f = blockIdx.x * 256 + threadIdx.x;    // one 4-dim group
    if (f >= N_ITEMS_PAD * (D / 4)) return;
    int row = f >> 4, c4 = f & 15;
    ushort4 o;
    if (row < N_ITEMS) {
        int node = N_USERS + row;
        int dg = deg[node]; if (dg < 1) dg = 1;
        float s = sqrtf((float)dg) * (1.f / 256.f);    // sqrt(deg)/(64 scale * 4 avg)
        float4 e4 = ((const float4*)(item_emb + (size_t)(row + 1) * D))[c4];
        size_t n4 = (size_t)node * 16 + c4;
        uchar4 a = ((const uchar4*)w1)[n4];
        uchar4 b = ((const uchar4*)w2)[n4];
        uchar4 c = ((const uchar4*)w3)[n4];
        o.x = f2bf(0.25f * e4.x + s * (fp82f(a.x) + fp82f(b.x) + fp82f(c.x)));
        o.y = f2bf(0.25f * e4.y + s * (fp82f(a.y) + fp82f(b.y) + fp82f(c.y)));
        o.z = f2bf(0.25f * e4.z + s * (fp82f(a.z) + fp82f(b.z) + fp82f(c.z)));
        o.w = f2bf(0.25f * e4.w + s * (fp82f(a.w) + fp82f(b.w) + fp82f(c.w)));
    } else {
        o.x = o.y = o.z = o.w = 0;   // pad rows -> score 0 -> exp = 1 (subtract 96 in k_loss)
    }
    ((ushort4*)item_bf)[f] = o;
}

// ---------------- pred (bf16 copy) + label score ----------------
__global__ __launch_bounds__(256) void k_pred(const int* __restrict__ user_seqs, const int* __restrict__ his,
                                              const int* __restrict__ next_items,
                                              const float* __restrict__ user_emb, const float* __restrict__ item_emb,
                                              const int* __restrict__ deg,
                                              const unsigned char* __restrict__ w1, const unsigned char* __restrict__ w2,
                                              const unsigned char* __restrict__ w3,
                                              ushort* __restrict__ pred_bf, float* __restrict__ slabel) {
    int b = blockIdx.x * 4 + (threadIdx.x >> 6);
    int lane = threadIdx.x & 63;
    int u = user_seqs[b];
    float hsum = 0.f; int cnt = 0;
    for (int j = 0; j < HIST; ++j) {
        int it = his[b * HIST + j];
        cnt += (it != 0);
        hsum += item_emb[(size_t)it * D + lane];   // item_emb[0] is all-zero (pad)
    }
    int du = deg[u]; if (du < 1) du = 1;
    float su = sqrtf((float)du) * (1.f / 256.f);
    size_t ur = (size_t)u * D + lane;
    float ulat = 0.25f * user_emb[ur] + su * (fp82f(w1[ur]) + fp82f(w2[ur]) + fp82f(w3[ur]));
    float pv = ulat + hsum / (float)cnt;
    pred_bf[(size_t)b * D + lane] = f2bf(pv);
    int lab = next_items[b] - 1;
    int node = N_USERS + lab;
    int di = deg[node]; if (di < 1) di = 1;
    float si = sqrtf((float)di) * (1.f / 256.f);
    size_t nr = (size_t)node * D + lane;
    float ilat = 0.25f * item_emb[(size_t)(lab + 1) * D + lane]
               + si * (fp82f(w1[nr]) + fp82f(w2[nr]) + fp82f(w3[nr]));
    float tv = pv * ilat;
#pragma unroll
    for (int off = 32; off > 0; off >>= 1) tv += __shfl_down(tv, off);
    if (lane == 0) slabel[b] = tv;
}

// ---------------- MFMA scores + max-free sumexp ----------------
__global__ __launch_bounds__(256) void k_scores(const ushort* __restrict__ item_bf,
                                                const ushort* __restrict__ pred_bf,
                                                float* __restrict__ sumexp) {
    __shared__ float lds[4 * 2048];  // 4 waves x 2048 floats = 32 KB
    int t = threadIdx.x, wv = t >> 6, lane = t & 63;
    for (int i = t; i < 4 * 2048; i += 256) lds[i] = 0.f;
    __syncthreads();

    int item0 = blockIdx.x * 128 + wv * 32 + (lane & 31);
    int khalf = (lane >> 5) * 8;   // which 8-elem k-half this lane holds

    const ushort* ib = item_bf + (size_t)item0 * D + khalf;
    short8 afrag[4];
#pragma unroll
    for (int tt = 0; tt < 4; ++tt) afrag[tt] = *(const short8*)(ib + 16 * tt);

    float* myld = lds + wv * 2048;
    for (int mi = 0; mi < 64; ++mi) {
        int mtile = mi * 32;
        const ushort* pb = pred_bf + (size_t)(mtile + (lane & 31)) * D + khalf;
        short8 b0 = *(const short8*)(pb);
        short8 b1 = *(const short8*)(pb + 16);
        short8 b2 = *(const short8*)(pb + 32);
        short8 b3 = *(const short8*)(pb + 48);
        float16 c = {0.f};
        c = __builtin_amdgcn_mfma_f32_32x32x16_bf16(afrag[0], b0, c, 0, 0, 0);
        c = __builtin_amdgcn_mfma_f32_32x32x16_bf16(afrag[1], b1, c, 0, 0, 0);
        c = __builtin_amdgcn_mfma_f32_32x32x16_bf16(afrag[2], b2, c, 0, 0, 0);
        c = __builtin_amdgcn_mfma_f32_32x32x16_bf16(afrag[3], b3, c, 0, 0, 0);
        float part = 0.f;
#pragma unroll
        for (int r = 0; r < 16; ++r) part += __expf(c[r]);
        part += __shfl_down(part, 32);          // fold the two col-duplicate half-waves
        if (lane < 32) {
            float* p = myld + mtile + lane;     // wave-private, conflict-free
            *p += part;
        }
    }
    __syncthreads();
    for (int m = t; m < 2048; m += 256) {
        float v = lds[m] + lds[2048 + m] + lds[4096 + m] + lds[6144 + m];
        unsafeAtomicAdd(&sumexp[m], v);
    }
}

// ---------------- final loss reduce ----------------
__global__ __launch_bounds__(256) void k_loss(const float* __restrict__ sumexp, const float* __restrict__ slabel,
                                              float* __restrict__ out) {
    __shared__ float ws[4];
    int t = threadIdx.x;
    float v = 0.f;
    for (int i = t; i < BATCH; i += 256)
        v += __logf(sumexp[i] - 96.0f) - slabel[i];   // -96: padded items contribute exp(0)=1 each
#pragma unroll
    for (int off = 32; off > 0; off >>= 1) v += __shfl_down(v, off);
    if ((t & 63) == 0) ws[t >> 6] = v;
    __syncthreads();
    if (t == 0) out[0] = (ws[0] + ws[1] + ws[2] + ws[3]) * (1.f / (float)BATCH);
}

extern "C" void kernel_launch(void* const* d_in, const int* in_sizes, int n_in,
                              void* d_out, int out_size, void* d_ws, size_t ws_size,
                              hipStream_t stream) {
    const int*   user_seqs = (const int*)d_in[0];
    const int*   his       = (const int*)d_in[1];
    const int*   next_itm  = (const int*)d_in[2];
    const int*   adj_row   = (const int*)d_in[3];
    const int*   adj_col   = (const int*)d_in[4];
    const float* user_emb  = (const float*)d_in[6];
    const float* item_emb  = (const float*)d_in[7];
    float* out = (float*)d_out;
    int nedges = in_sizes[3];   // 12,800,000

    // Workspace layout (~170 MB)
    unsigned char* w0 = (unsigned char*)d_ws;              // 12.8 MB each
    unsigned char* w1 = w0 + (size_t)N_NODES * D;
    unsigned char* w2 = w1 + (size_t)N_NODES * D;
    unsigned char* w3 = w2 + (size_t)N_NODES * D;
    float*  slabel = (float*)(w3 + (size_t)N_NODES * D);   // 2,048
    float*  sumexp = slabel + BATCH;                       // 2,048   (zeroed)
    int*    btot   = (int*)(sumexp + BATCH);               // 392     (zeroed)
    int*    bbase  = btot + 392;                           // 392
    int*    gcursor= bbase + 392;                          // 392
    int*    rowptr = gcursor + 392;                        // 200,002
    int*    deg    = rowptr + (N_NODES + 2);               // 200,000
    int*    staged = deg + N_NODES;                        // 12.8M ints (51.2 MB)
    int*    ecols  = staged + (size_t)nedges;              // 12.8M ints (51.2 MB)
    ushort* item_bf = (ushort*)(ecols + (size_t)nedges);   // 100096*64 ushort
    ushort* pred_bf = item_bf + (size_t)N_ITEMS_PAD * D;   // 131072 ushort

    // zero sumexp + btot in one shot (contiguous)
    hipError_t _e = hipMemsetAsync(sumexp, 0, (size_t)(BATCH + 392) * sizeof(int), stream);
    (void)_e;

    int nchunks = (nedges + CHUNK - 1) / CHUNK;
    k_bucket_hist<<<nchunks, 256, 0, stream>>>(adj_row, btot, nedges);
    k_bucket_scan<<<1, 256, 0, stream>>>(btot, bbase, gcursor, nedges);
    k_scatter_a<<<nchunks, 256, 0, stream>>>(adj_row, adj_col, gcursor, staged, nedges);
    k_scatter_b<<<N_BUCKETS, 256, 0, stream>>>(bbase, staged, ecols, rowptr, deg);

    k_init<<<(N_NODES * (D / 4) + 255) / 256, 256, 0, stream>>>(user_emb, item_emb, deg, w0);

    k_prop<<<N_NODES / 4, 256, 0, stream>>>(rowptr, ecols, w0, w1);
    k_prop<<<N_NODES / 4, 256, 0, stream>>>(rowptr, ecols, w1, w2);
    k_prop<<<N_NODES / 4, 256, 0, stream>>>(rowptr, ecols, w2, w3);

    k_conv_items<<<(N_ITEMS_PAD * (D / 4) + 255) / 256, 256, 0, stream>>>(item_emb, deg, w1, w2, w3, item_bf);
    k_pred<<<BATCH / 4, 256, 0, stream>>>(user_seqs, his, next_itm, user_emb, item_emb, deg,
                                          w1, w2, w3, pred_bf, slabel);

    k_scores<<<N_ITEMS_PAD / 128, 256, 0, stream>>>(item_bf, pred_bf, sumexp);

    k_loss<<<1, 256, 0, stream>>>(sumexp, slabel, out);
}

// Round 9
// 780.949 us; speedup vs baseline: 1.9617x; 1.0125x over previous
//
#include <hip/hip_runtime.h>
#include <hip/hip_bf16.h>
#include <cstddef>

// Problem constants (fixed by reference)
#define N_USERS   100000
#define N_ITEMS   100000
#define N_NODES   200000
#define D         64
#define BATCH     2048
#define HIST      50
#define N_ITEMS_PAD 100096   // padded to multiple of 128 (block item-chunk)

#define BUCKET_SHIFT 9                       // 512 rows per bucket
#define N_BUCKETS ((N_NODES + 511) >> 9)     // 391
#define CHUNK 16384                          // edges per binning block

#define MSLICE 512                           // batch rows per k_scores block

typedef __attribute__((ext_vector_type(8))) short short8;
typedef __attribute__((ext_vector_type(16))) float float16;

__device__ __forceinline__ ushort f2bf(float x) {  // fp32 -> bf16 RNE
    unsigned u = __float_as_uint(x);
    return (ushort)((u + 0x7FFF + ((u >> 16) & 1)) >> 16);
}
__device__ __forceinline__ unsigned char f2fp8(float x) {  // fp32 -> fp8 e4m3 (OCP), RNE+sat
    int p = __builtin_amdgcn_cvt_pk_fp8_f32(x, x, 0, false);
    return (unsigned char)(p & 0xFF);
}
__device__ __forceinline__ float fp82f(unsigned char u) {  // fp8 e4m3 -> fp32
    return __builtin_amdgcn_cvt_f32_fp8((int)u, 0);
}

// ---------------- bucket histogram: 391 counters, LDS-aggregated ----------------
__global__ __launch_bounds__(256) void k_bucket_hist(const int* __restrict__ adj_row,
                                                     int* __restrict__ btot, int nedges) {
    __shared__ int counts[N_BUCKETS];
    int t = threadIdx.x;
    int base = blockIdx.x * CHUNK;
    for (int i = t; i < N_BUCKETS; i += 256) counts[i] = 0;
    __syncthreads();
    for (int k = 0; k < CHUNK / 256; ++k) {
        int e = base + k * 256 + t;
        if (e < nedges) atomicAdd(&counts[adj_row[e] >> BUCKET_SHIFT], 1);
    }
    __syncthreads();
    for (int i = t; i < N_BUCKETS; i += 256) {
        int c = counts[i];
        if (c) atomicAdd(&btot[i], c);
    }
}

// ---------------- scan 391 bucket totals -> bases; seed arena cursors ----------------
__global__ __launch_bounds__(256) void k_bucket_scan(const int* __restrict__ btot,
                                                     int* __restrict__ bbase, int* __restrict__ gcursor,
                                                     int nedges) {
    __shared__ int s[256];
    int t = threadIdx.x;
    int v0 = (2 * t     < N_BUCKETS) ? btot[2 * t]     : 0;
    int v1 = (2 * t + 1 < N_BUCKETS) ? btot[2 * t + 1] : 0;
    int sum = v0 + v1;
    s[t] = sum; __syncthreads();
    for (int off = 1; off < 256; off <<= 1) {
        int v = (t >= off) ? s[t - off] : 0;
        __syncthreads();
        s[t] += v;
        __syncthreads();
    }
    int excl = s[t] - sum;
    if (2 * t < N_BUCKETS)     { bbase[2 * t]     = excl;      gcursor[2 * t]     = excl; }
    if (2 * t + 1 < N_BUCKETS) { bbase[2 * t + 1] = excl + v0; gcursor[2 * t + 1] = excl + v0; }
    if (t == 0) bbase[N_BUCKETS] = nedges;
}

// ---------------- scatter pass A: bin edges into bucket arenas (contiguous runs) ----------------
// staged record = (row&511)<<18 | col  (27 bits)
__global__ __launch_bounds__(256) void k_scatter_a(const int* __restrict__ adj_row, const int* __restrict__ adj_col,
                                                   int* __restrict__ gcursor, int* __restrict__ staged, int nedges) {
    __shared__ int counts[N_BUCKETS];
    __shared__ int cursors[N_BUCKETS];
    int t = threadIdx.x;
    int base = blockIdx.x * CHUNK;
    for (int i = t; i < N_BUCKETS; i += 256) counts[i] = 0;
    __syncthreads();
    for (int k = 0; k < CHUNK / 256; ++k) {
        int e = base + k * 256 + t;
        if (e < nedges) atomicAdd(&counts[adj_row[e] >> BUCKET_SHIFT], 1);
    }
    __syncthreads();
    for (int b = t; b < N_BUCKETS; b += 256) {
        int c = counts[b];
        cursors[b] = (c > 0) ? atomicAdd(&gcursor[b], c) : 0;
    }
    __syncthreads();
    for (int k = 0; k < CHUNK / 256; ++k) {
        int e = base + k * 256 + t;
        if (e < nedges) {
            int r = adj_row[e];
            int b = r >> BUCKET_SHIFT;
            int p = atomicAdd(&cursors[b], 1);
            staged[p] = ((r & 511) << 18) | adj_col[e];
        }
    }
}

// ---------------- scatter pass B: per bucket, build rowptr+deg via LDS scan, place edges ----------------
__global__ __launch_bounds__(256) void k_scatter_b(const int* __restrict__ bbase, const int* __restrict__ staged,
                                                   int* __restrict__ ecols, int* __restrict__ rowptr,
                                                   int* __restrict__ deg) {
    __shared__ int cnt[512];
    __shared__ int ts[256];
    __shared__ int cur[512];
    int b = blockIdx.x, t = threadIdx.x;
    cnt[t] = 0; cnt[t + 256] = 0;
    __syncthreads();
    int es = bbase[b], ee = bbase[b + 1];
    for (int e = es + t; e < ee; e += 256) atomicAdd(&cnt[staged[e] >> 18], 1);
    __syncthreads();
    int c0 = cnt[2 * t], c1 = cnt[2 * t + 1];
    int sum = c0 + c1;
    ts[t] = sum; __syncthreads();
    for (int off = 1; off < 256; off <<= 1) {
        int v = (t >= off) ? ts[t - off] : 0;
        __syncthreads();
        ts[t] += v;
        __syncthreads();
    }
    int excl = ts[t] - sum;
    int r0 = b << BUCKET_SHIFT;
    int g0 = es + excl, g1 = es + excl + c0;
    if (r0 + 2 * t < N_NODES)     { rowptr[r0 + 2 * t]     = g0; deg[r0 + 2 * t]     = c0; }
    if (r0 + 2 * t + 1 < N_NODES) { rowptr[r0 + 2 * t + 1] = g1; deg[r0 + 2 * t + 1] = c1; }
    cur[2 * t] = g0; cur[2 * t + 1] = g1;
    if (b == N_BUCKETS - 1 && t == 0) rowptr[N_NODES] = ee;
    __syncthreads();
    for (int e = es + t; e < ee; e += 256) {
        int v = staged[e];
        int pos = atomicAdd(&cur[v >> 18], 1);
        ecols[pos] = (v & 0x3FFFF) << 6;   // byte offset into fp8 node rows
    }
}

// ---------------- init: w0 = fp8( 64 * x0 / sqrt(max(deg,1)) )  (z-space, scaled by 64) ----------------
__global__ void k_init(const float* __restrict__ user_emb, const float* __restrict__ item_emb,
                       const int* __restrict__ deg, unsigned char* __restrict__ w0) {
    int f = blockIdx.x * 256 + threadIdx.x;              // one 4-dim group
    if (f >= N_NODES * (D / 4)) return;
    int row = f >> 4;
    const float4* src = (row < N_USERS)
        ? ((const float4*)user_emb) + (size_t)row * 16 + (f & 15)
        : ((const float4*)item_emb) + (size_t)(row - (N_USERS - 1)) * 16 + (f & 15);
    float4 v = *src;
    int dg = deg[row]; if (dg < 1) dg = 1;
    float sc = 64.f * __frsqrt_rn((float)dg);
    uchar4 o;
    o.x = f2fp8(v.x * sc); o.y = f2fp8(v.y * sc);
    o.z = f2fp8(v.z * sc); o.w = f2fp8(v.w * sc);
    ((uchar4*)w0)[f] = o;
}

// ---------------- propagate (fp8 z-space): w_out[r] = (1/deg_r) * sum w_in[c] ----------------
// lane layout: slot = lane>>4 picks one of 4 edges, d4 = (lane&15)*4 picks 4 dims.
__global__ __launch_bounds__(256) void k_prop(const int* __restrict__ rowptr, const int* __restrict__ ecols,
                                              const unsigned char* __restrict__ x_in,
                                              unsigned char* __restrict__ x_out) {
    int w = blockIdx.x * 4 + (threadIdx.x >> 6);
    int lane = threadIdx.x & 63;
    int slot = lane >> 4;
    int d4 = (lane & 15) * 4;
    const unsigned char* xb = x_in + d4;    // loop-invariant base for this lane's dims
    int s = rowptr[w], e = rowptr[w + 1];
    float ax = 0.f, ay = 0.f, az = 0.f, aw = 0.f;
    int p = s;
    for (; p + 16 <= e; p += 16) {
        int c0 = ecols[p + slot];
        int c1 = ecols[p + 4 + slot];
        int c2 = ecols[p + 8 + slot];
        int c3 = ecols[p + 12 + slot];
        unsigned b0 = *(const unsigned*)(xb + c0);
        unsigned b1 = *(const unsigned*)(xb + c1);
        unsigned b2 = *(const unsigned*)(xb + c2);
        unsigned b3 = *(const unsigned*)(xb + c3);
        ax += __builtin_amdgcn_cvt_f32_fp8((int)b0, 0);
        ay += __builtin_amdgcn_cvt_f32_fp8((int)b0, 1);
        az += __builtin_amdgcn_cvt_f32_fp8((int)b0, 2);
        aw += __builtin_amdgcn_cvt_f32_fp8((int)b0, 3);
        ax += __builtin_amdgcn_cvt_f32_fp8((int)b1, 0);
        ay += __builtin_amdgcn_cvt_f32_fp8((int)b1, 1);
        az += __builtin_amdgcn_cvt_f32_fp8((int)b1, 2);
        aw += __builtin_amdgcn_cvt_f32_fp8((int)b1, 3);
        ax += __builtin_amdgcn_cvt_f32_fp8((int)b2, 0);
        ay += __builtin_amdgcn_cvt_f32_fp8((int)b2, 1);
        az += __builtin_amdgcn_cvt_f32_fp8((int)b2, 2);
        aw += __builtin_amdgcn_cvt_f32_fp8((int)b2, 3);
        ax += __builtin_amdgcn_cvt_f32_fp8((int)b3, 0);
        ay += __builtin_amdgcn_cvt_f32_fp8((int)b3, 1);
        az += __builtin_amdgcn_cvt_f32_fp8((int)b3, 2);
        aw += __builtin_amdgcn_cvt_f32_fp8((int)b3, 3);
    }
    for (; p < e; p += 4) {
        int rem = e - p;                       // >= 1
        int sl = (slot < rem) ? slot : 0;
        int col = ecols[p + sl];
        unsigned b = *(const unsigned*)(xb + col);
        if (slot < rem) {
            ax += __builtin_amdgcn_cvt_f32_fp8((int)b, 0);
            ay += __builtin_amdgcn_cvt_f32_fp8((int)b, 1);
            az += __builtin_amdgcn_cvt_f32_fp8((int)b, 2);
            aw += __builtin_amdgcn_cvt_f32_fp8((int)b, 3);
        }
    }
    // cross-slot reduce: lanes L, L+16, L+32, L+48 hold same dims, different edges
    ax += __shfl_down(ax, 32); ay += __shfl_down(ay, 32);
    az += __shfl_down(az, 32); aw += __shfl_down(aw, 32);
    ax += __shfl_down(ax, 16); ay += __shfl_down(ay, 16);
    az += __shfl_down(az, 16); aw += __shfl_down(aw, 16);
    if (lane < 16) {
        int cnt = e - s;
        float inv = (cnt > 0) ? 1.f / (float)cnt : 0.f;
        uchar4 o;
        o.x = f2fp8(ax * inv); o.y = f2fp8(ay * inv);
        o.z = f2fp8(az * inv); o.w = f2fp8(aw * inv);
        *(uchar4*)(x_out + (size_t)w * D + d4) = o;
    }
}

// ---------------- item latents: bf16( 0.25*item_emb + sqrt(deg)/256*(w1+w2+w3) ), zero-pad ----------------
__global__ void k_conv_items(const float* __restrict__ item_emb, const int* __restrict__ deg,
                             const unsigned char* __restrict__ w1, const unsigned char* __restrict__ w2,
                             const unsigned char* __restrict__ w3, ushort* __restrict__ item_bf) {
    int f = blockIdx.x * 256 + threadIdx.x;    // one 4-dim group
    if (f >= N_ITEMS_PAD * (D / 4)) return;
    int row = f >> 4, c4 = f & 15;
    ushort4 o;
    if (row < N_ITEMS) {
        int node = N_USERS + row;
        int dg = deg[node]; if (dg < 1) dg = 1;
        float s = sqrtf((float)dg) * (1.f / 256.f);    // sqrt(deg)/(64 scale * 4 avg)
        float4 e4 = ((const float4*)(item_emb + (size_t)(row + 1) * D))[c4];
        size_t n4 = (size_t)node * 16 + c4;
        uchar4 a = ((const uchar4*)w1)[n4];
        uchar4 b = ((const uchar4*)w2)[n4];
        uchar4 c = ((const uchar4*)w3)[n4];
        o.x = f2bf(0.25f * e4.x + s * (fp82f(a.x) + fp82f(b.x) + fp82f(c.x)));
        o.y = f2bf(0.25f * e4.y + s * (fp82f(a.y) + fp82f(b.y) + fp82f(c.y)));
        o.z = f2bf(0.25f * e4.z + s * (fp82f(a.z) + fp82f(b.z) + fp82f(c.z)));
        o.w = f2bf(0.25f * e4.w + s * (fp82f(a.w) + fp82f(b.w) + fp82f(c.w)));
    } else {
        o.x = o.y = o.z = o.w = 0;   // pad rows -> score 0 -> exp = 1 (subtract 96 in k_loss)
    }
    ((ushort4*)item_bf)[f] = o;
}

// ---------------- pred (bf16 copy) + label score ----------------
__global__ __launch_bounds__(256) void k_pred(const int* __restrict__ user_seqs, const int* __restrict__ his,
                                              const int* __restrict__ next_items,
                                              const float* __restrict__ user_emb, const float* __restrict__ item_emb,
                                              const int* __restrict__ deg,
                                              const unsigned char* __restrict__ w1, const unsigned char* __restrict__ w2,
                                              const unsigned char* __restrict__ w3,
                                              ushort* __restrict__ pred_bf, float* __restrict__ slabel) {
    int b = blockIdx.x * 4 + (threadIdx.x >> 6);
    int lane = threadIdx.x & 63;
    int u = user_seqs[b];
    float hsum = 0.f; int cnt = 0;
    for (int j = 0; j < HIST; ++j) {
        int it = his[b * HIST + j];
        cnt += (it != 0);
        hsum += item_emb[(size_t)it * D + lane];   // item_emb[0] is all-zero (pad)
    }
    int du = deg[u]; if (du < 1) du = 1;
    float su = sqrtf((float)du) * (1.f / 256.f);
    size_t ur = (size_t)u * D + lane;
    float ulat = 0.25f * user_emb[ur] + su * (fp82f(w1[ur]) + fp82f(w2[ur]) + fp82f(w3[ur]));
    float pv = ulat + hsum / (float)cnt;
    pred_bf[(size_t)b * D + lane] = f2bf(pv);
    int lab = next_items[b] - 1;
    int node = N_USERS + lab;
    int di = deg[node]; if (di < 1) di = 1;
    float si = sqrtf((float)di) * (1.f / 256.f);
    size_t nr = (size_t)node * D + lane;
    float ilat = 0.25f * item_emb[(size_t)(lab + 1) * D + lane]
               + si * (fp82f(w1[nr]) + fp82f(w2[nr]) + fp82f(w3[nr]));
    float tv = pv * ilat;
#pragma unroll
    for (int off = 32; off > 0; off >>= 1) tv += __shfl_down(tv, off);
    if (lane == 0) slabel[b] = tv;
}

// ---------------- MFMA scores + max-free sumexp ----------------
// grid = (N_ITEMS_PAD/128, BATCH/MSLICE); block covers 128 items x 512 batch rows.
// LDS = 4 waves x 512 floats = 8 KB -> high occupancy (R8: 32KB LDS capped us at ~28%).
__global__ __launch_bounds__(256) void k_scores(const ushort* __restrict__ item_bf,
                                                const ushort* __restrict__ pred_bf,
                                                float* __restrict__ sumexp) {
    __shared__ float lds[4 * MSLICE];  // 8 KB
    int t = threadIdx.x, wv = t >> 6, lane = t & 63;
    for (int i = t; i < 4 * MSLICE; i += 256) lds[i] = 0.f;
    __syncthreads();

    int item0 = blockIdx.x * 128 + wv * 32 + (lane & 31);
    int khalf = (lane >> 5) * 8;   // which 8-elem k-half this lane holds

    const ushort* ib = item_bf + (size_t)item0 * D + khalf;
    short8 afrag[4];
#pragma unroll
    for (int tt = 0; tt < 4; ++tt) afrag[tt] = *(const short8*)(ib + 16 * tt);

    int bbase = blockIdx.y * MSLICE;
    float* myld = lds + wv * MSLICE;
    for (int mi = 0; mi < MSLICE / 32; ++mi) {
        int mtile = mi * 32;
        const ushort* pb = pred_bf + (size_t)(bbase + mtile + (lane & 31)) * D + khalf;
        short8 b0 = *(const short8*)(pb);
        short8 b1 = *(const short8*)(pb + 16);
        short8 b2 = *(const short8*)(pb + 32);
        short8 b3 = *(const short8*)(pb + 48);
        float16 c = {0.f};
        c = __builtin_amdgcn_mfma_f32_32x32x16_bf16(afrag[0], b0, c, 0, 0, 0);
        c = __builtin_amdgcn_mfma_f32_32x32x16_bf16(afrag[1], b1, c, 0, 0, 0);
        c = __builtin_amdgcn_mfma_f32_32x32x16_bf16(afrag[2], b2, c, 0, 0, 0);
        c = __builtin_amdgcn_mfma_f32_32x32x16_bf16(afrag[3], b3, c, 0, 0, 0);
        float part = 0.f;
#pragma unroll
        for (int r = 0; r < 16; ++r) part += __expf(c[r]);
        part += __shfl_down(part, 32);          // fold the two col-duplicate half-waves
        if (lane < 32) {
            float* p = myld + mtile + lane;     // wave-private, conflict-free
            *p += part;
        }
    }
    __syncthreads();
    for (int m = t; m < MSLICE; m += 256) {
        float v = lds[m] + lds[MSLICE + m] + lds[2 * MSLICE + m] + lds[3 * MSLICE + m];
        unsafeAtomicAdd(&sumexp[bbase + m], v);
    }
}

// ---------------- final loss reduce ----------------
__global__ __launch_bounds__(256) void k_loss(const float* __restrict__ sumexp, const float* __restrict__ slabel,
                                              float* __restrict__ out) {
    __shared__ float ws[4];
    int t = threadIdx.x;
    float v = 0.f;
    for (int i = t; i < BATCH; i += 256)
        v += __logf(sumexp[i] - 96.0f) - slabel[i];   // -96: padded items contribute exp(0)=1 each
#pragma unroll
    for (int off = 32; off > 0; off >>= 1) v += __shfl_down(v, off);
    if ((t & 63) == 0) ws[t >> 6] = v;
    __syncthreads();
    if (t == 0) out[0] = (ws[0] + ws[1] + ws[2] + ws[3]) * (1.f / (float)BATCH);
}

extern "C" void kernel_launch(void* const* d_in, const int* in_sizes, int n_in,
                              void* d_out, int out_size, void* d_ws, size_t ws_size,
                              hipStream_t stream) {
    const int*   user_seqs = (const int*)d_in[0];
    const int*   his       = (const int*)d_in[1];
    const int*   next_itm  = (const int*)d_in[2];
    const int*   adj_row   = (const int*)d_in[3];
    const int*   adj_col   = (const int*)d_in[4];
    const float* user_emb  = (const float*)d_in[6];
    const float* item_emb  = (const float*)d_in[7];
    float* out = (float*)d_out;
    int nedges = in_sizes[3];   // 12,800,000

    // Workspace layout (~170 MB)
    unsigned char* w0 = (unsigned char*)d_ws;              // 12.8 MB each
    unsigned char* w1 = w0 + (size_t)N_NODES * D;
    unsigned char* w2 = w1 + (size_t)N_NODES * D;
    unsigned char* w3 = w2 + (size_t)N_NODES * D;
    float*  slabel = (float*)(w3 + (size_t)N_NODES * D);   // 2,048
    float*  sumexp = slabel + BATCH;                       // 2,048   (zeroed)
    int*    btot   = (int*)(sumexp + BATCH);               // 392     (zeroed)
    int*    bbase  = btot + 392;                           // 392
    int*    gcursor= bbase + 392;                          // 392
    int*    rowptr = gcursor + 392;                        // 200,002
    int*    deg    = rowptr + (N_NODES + 2);               // 200,000
    int*    staged = deg + N_NODES;                        // 12.8M ints (51.2 MB)
    int*    ecols  = staged + (size_t)nedges;              // 12.8M ints (51.2 MB)
    ushort* item_bf = (ushort*)(ecols + (size_t)nedges);   // 100096*64 ushort
    ushort* pred_bf = item_bf + (size_t)N_ITEMS_PAD * D;   // 131072 ushort

    // zero sumexp + btot in one shot (contiguous)
    hipError_t _e = hipMemsetAsync(sumexp, 0, (size_t)(BATCH + 392) * sizeof(int), stream);
    (void)_e;

    int nchunks = (nedges + CHUNK - 1) / CHUNK;
    k_bucket_hist<<<nchunks, 256, 0, stream>>>(adj_row, btot, nedges);
    k_bucket_scan<<<1, 256, 0, stream>>>(btot, bbase, gcursor, nedges);
    k_scatter_a<<<nchunks, 256, 0, stream>>>(adj_row, adj_col, gcursor, staged, nedges);
    k_scatter_b<<<N_BUCKETS, 256, 0, stream>>>(bbase, staged, ecols, rowptr, deg);

    k_init<<<(N_NODES * (D / 4) + 255) / 256, 256, 0, stream>>>(user_emb, item_emb, deg, w0);

    k_prop<<<N_NODES / 4, 256, 0, stream>>>(rowptr, ecols, w0, w1);
    k_prop<<<N_NODES / 4, 256, 0, stream>>>(rowptr, ecols, w1, w2);
    k_prop<<<N_NODES / 4, 256, 0, stream>>>(rowptr, ecols, w2, w3);

    k_conv_items<<<(N_ITEMS_PAD * (D / 4) + 255) / 256, 256, 0, stream>>>(item_emb, deg, w1, w2, w3, item_bf);
    k_pred<<<BATCH / 4, 256, 0, stream>>>(user_seqs, his, next_itm, user_emb, item_emb, deg,
                                          w1, w2, w3, pred_bf, slabel);

    dim3 gs(N_ITEMS_PAD / 128, BATCH / MSLICE);
    k_scores<<<gs, 256, 0, stream>>>(item_bf, pred_bf, sumexp);

    k_loss<<<1, 256, 0, stream>>>(sumexp, slabel, out);
}